// Round 1
// 655.993 us; speedup vs baseline: 1.0695x; 1.0695x over previous
//
#include <hip/hip_runtime.h>
#include <math.h>

// ---------------- common helpers ----------------
typedef short bf16x8 __attribute__((ext_vector_type(8)));
typedef float f32x4 __attribute__((ext_vector_type(4)));

#define LOG2E 1.4426950408889634f
#define GSCALE 0.6451712903225806f   /* 1 - 11/31 + 1e-5 */

__device__ __forceinline__ float bf2f(unsigned short h) {
    union { unsigned u; float f; } v; v.u = ((unsigned)h) << 16; return v.f;
}
__device__ __forceinline__ unsigned short f2bf(float f) {
    union { float f; unsigned u; } v; v.f = f;
    unsigned r = v.u + 0x7FFFu + ((v.u >> 16) & 1u);
    return (unsigned short)(r >> 16);
}

#define GLD16(lds, g)                                                          \
    __builtin_amdgcn_global_load_lds(                                          \
        (const __attribute__((address_space(1))) void*)(g),                    \
        (__attribute__((address_space(3))) void*)(lds), 16, 0, 0)

#define MFMA16(a, b, c) __builtin_amdgcn_mfma_f32_16x16x32_bf16(a, b, c, 0, 0, 0)

// ---------------- fused f32 -> bf16 conversion (4 srcs, contiguous dst) ----
struct us4 { unsigned short a, b, c, d; };
__global__ __launch_bounds__(256) void cvt4_f32_bf16(
    const float* __restrict__ s0, const float* __restrict__ s1,
    const float* __restrict__ s2, const float* __restrict__ s3,
    unsigned short* __restrict__ dst, int c0, int c1, int c2, int n4)
{
    int i = blockIdx.x * 256 + threadIdx.x;
    if (i >= n4) return;
    const float* s; int off;
    if (i < c0)      { s = s0; off = i; }
    else if (i < c1) { s = s1; off = i - c0; }
    else if (i < c2) { s = s2; off = i - c1; }
    else             { s = s3; off = i - c2; }
    float4 v = ((const float4*)s)[off];
    us4 o = { f2bf(v.x), f2bf(v.y), f2bf(v.z), f2bf(v.w) };
    ((us4*)dst)[i] = o;
}

// ---------------- 256x256 8-phase GEMM: C = A @ Bt^T (bf16, f32 acc) -------
// 8 waves (2M x 4N), per-wave 128x64 output, BK=64, double-buffered 128 KiB
// LDS, global_load_lds staging with XOR-8 source pre-swizzle (linear LDS
// dest, swizzled ds_read -> conflict-free), counted vmcnt(6) at phases 4/8,
// raw s_barrier + setprio(1) around MFMA clusters.
// EPI 0: col<6144 -> scatter Q/K/V [b][h][t][d]; col>=6144 -> sigmoid -> Gb
// EPI 2: plain f32 -> C
template <int EPI>
__global__ __launch_bounds__(512, 2) void gemm256(
    const unsigned short* __restrict__ A, const unsigned short* __restrict__ Bt,
    void* __restrict__ Cv,
    unsigned short* __restrict__ Qp, unsigned short* __restrict__ Kp,
    unsigned short* __restrict__ Vp, unsigned short* __restrict__ Gb,
    int M, int N, int K)
{
    __shared__ __attribute__((aligned(16))) unsigned short lA[2][16384];
    __shared__ __attribute__((aligned(16))) unsigned short lB[2][16384];

    const int tid  = threadIdx.x;
    const int lane = tid & 63, wave = tid >> 6;
    const int quad = lane >> 4, lr = lane & 15;
    const int wm   = (wave >> 2) * 128;   // 0 / 128
    const int wn   = (wave & 3) * 64;     // 0 / 64 / 128 / 192
    const int lsw  = lr & 7;

    // XCD-aware bijective block swizzle (nwg % 8 == 0 for all our launches)
    const int nwg = (int)(gridDim.x * gridDim.y);
    const int lin = (int)(blockIdx.y * gridDim.x + blockIdx.x);
    const int swz = (lin & 7) * (nwg >> 3) + (lin >> 3);
    const int bn = swz % (int)gridDim.x, bm = swz / (int)gridDim.x;

    const unsigned short* Ab = A  + (long long)bm * 256 * K;
    const unsigned short* Bb = Bt + (long long)bn * 256 * K;

    // staging geometry: half-tile = 128 rows x 64 cols bf16 = 16 KiB
    // = 2 sweeps x (512 thr x 16B). LDS dest linear; global src pre-swizzled
    // so LDS slot g of row r holds global group g^(r&7).
    const int c0r = tid, c1r = 512 + tid;
    const int row0 = c0r >> 3, row1 = c1r >> 3;
    const long long ga0 = (long long)row0 * K + ((c0r & 7) ^ (row0 & 7)) * 8;
    const long long ga1 = (long long)row1 * K + ((c1r & 7) ^ (row1 & 7)) * 8;
    const long long HK  = (long long)128 * K;
    const int l0 = c0r * 8, l1 = c1r * 8;

#define STAGE(ldsb, gb, half, kt)                                              \
    do {                                                                       \
        GLD16((ldsb) + (half) * 8192 + l0, (gb) + (half) * HK + (kt) + ga0);   \
        GLD16((ldsb) + (half) * 8192 + l1, (gb) + (half) * HK + (kt) + ga1);   \
    } while (0)

    f32x4 acc[8][4] = {};
    bf16x8 a[4][2], blo[2][2], bhi[2][2];

#define LOADA(buf, base)                                                       \
    _Pragma("unroll") for (int i = 0; i < 4; ++i)                              \
    _Pragma("unroll") for (int s = 0; s < 2; ++s)                              \
        a[i][s] = *(const bf16x8*)((buf) + ((base) + i * 16 + lr) * 64 +       \
                                   (((s * 4 + quad) ^ lsw) * 8));
#define LOADB(dst, buf, base)                                                  \
    _Pragma("unroll") for (int j = 0; j < 2; ++j)                              \
    _Pragma("unroll") for (int s = 0; s < 2; ++s)                              \
        dst[j][s] = *(const bf16x8*)((buf) + ((base) + j * 16 + lr) * 64 +     \
                                     (((s * 4 + quad) ^ lsw) * 8));
#define MFMAQ(MQ, NQ, BV)                                                      \
    _Pragma("unroll") for (int i = 0; i < 4; ++i)                              \
    _Pragma("unroll") for (int j = 0; j < 2; ++j)                              \
    _Pragma("unroll") for (int s = 0; s < 2; ++s)                              \
        acc[(MQ) * 4 + i][(NQ) * 2 + j] =                                      \
            MFMA16(a[i][s], BV[j][s], acc[(MQ) * 4 + i][(NQ) * 2 + j]);

#define BARR()  asm volatile("s_barrier" ::: "memory")
#define LGKM0() asm volatile("s_waitcnt lgkmcnt(0)" ::: "memory")
#define VM6()   asm volatile("s_waitcnt vmcnt(6)" ::: "memory")
#define PTAIL() do { BARR(); LGKM0(); __builtin_amdgcn_sched_barrier(0);       \
                     __builtin_amdgcn_s_setprio(1); } while (0)
#define PEND()  do { __builtin_amdgcn_s_setprio(0); BARR(); } while (0)

    // ---- prologue: tile0 {A0,A1,B0,B1} + tile1 {B0,B1,A0}; A1(1) in P1 ----
    STAGE(lA[0], Ab, 0, 0); STAGE(lA[0], Ab, 1, 0);
    STAGE(lB[0], Bb, 0, 0); STAGE(lB[0], Bb, 1, 0);
    STAGE(lB[1], Bb, 0, 64); STAGE(lB[1], Bb, 1, 64);
    STAGE(lA[1], Ab, 0, 64);
    VM6();          // tile0's 8 loads complete; tile1's 6 remain in flight
    BARR();

    const int NT = K >> 6;
    for (int it = 0; it < (NT >> 1); ++it) {
        const int v   = 2 * it + 1;
        const int kn0 = (2 * it + 2 < NT) ? (2 * it + 2) * 64 : 0; // clamp tail
        const int kn1 = (2 * it + 3 < NT) ? (2 * it + 3) * 64 : 0;
        // ---- P1: Q(lo,lo) of tile u; issue A1(v) ----
        LOADA(lA[0], wm); LOADB(blo, lB[0], wn);
        STAGE(lA[1], Ab, 1, v * 64);
        PTAIL(); MFMAQ(0, 0, blo); PEND();
        // ---- P2: Q(lo,hi) ----
        LOADB(bhi, lB[0], wn + 32);
        PTAIL(); MFMAQ(0, 1, bhi); PEND();
        // ---- P3: Q(hi,hi); issue B0(u+2) (buf0 B reads ended P2) ----
        LOADA(lA[0], wm + 64);
        STAGE(lB[0], Bb, 0, kn0);
        PTAIL(); MFMAQ(1, 1, bhi); PEND();
        // ---- P4: Q(hi,lo); issue B1,A0(u+2); vmcnt(6) -> tile v ready ----
        STAGE(lB[0], Bb, 1, kn0); STAGE(lA[0], Ab, 0, kn0);
        VM6(); BARR();
        __builtin_amdgcn_s_setprio(1); MFMAQ(1, 0, blo); PEND();
        // ---- P5: Q(lo,lo) of tile v; issue A1(u+2) (buf0 A reads ended P3) --
        LOADA(lA[1], wm); LOADB(blo, lB[1], wn);
        STAGE(lA[0], Ab, 1, kn0);
        PTAIL(); MFMAQ(0, 0, blo); PEND();
        // ---- P6: Q(lo,hi) ----
        LOADB(bhi, lB[1], wn + 32);
        PTAIL(); MFMAQ(0, 1, bhi); PEND();
        // ---- P7: Q(hi,hi); issue B0(v+2) ----
        LOADA(lA[1], wm + 64);
        STAGE(lB[1], Bb, 0, kn1);
        PTAIL(); MFMAQ(1, 1, bhi); PEND();
        // ---- P8: Q(hi,lo); issue B1,A0(v+2); vmcnt(6) -> tile u+2 ready ----
        STAGE(lB[1], Bb, 1, kn1); STAGE(lA[1], Ab, 0, kn1);
        VM6(); BARR();
        __builtin_amdgcn_s_setprio(1); MFMAQ(1, 0, blo); PEND();
    }
    asm volatile("s_waitcnt vmcnt(0)" ::: "memory");  // drain before LDS dealloc

    // ---- epilogue ----
#pragma unroll
    for (int i = 0; i < 8; ++i)
#pragma unroll
        for (int j = 0; j < 4; ++j)
#pragma unroll
            for (int r = 0; r < 4; ++r) {
                int row = bm * 256 + wm + i * 16 + quad * 4 + r;
                int col = bn * 256 + wn + j * 16 + lr;
                float vv = acc[i][j][r];
                if (EPI == 0) {
                    if (col < 6144) {
                        int tens = col >> 11, h = (col >> 7) & 15, e = col & 127;
                        int b = row >> 12, t = row & 4095;
                        long long dst = (((long long)(b * 16 + h)) * 4096 + t) * 128 + e;
                        unsigned short* P = (tens == 0) ? Qp : ((tens == 1) ? Kp : Vp);
                        P[dst] = f2bf(vv);
                    } else {
                        vv = 1.0f / (1.0f + __expf(-vv));
                        Gb[(long long)row * 2048 + (col - 6144)] = f2bf(vv);
                    }
                } else {
                    ((float*)Cv)[(long long)row * N + col] = vv;
                }
            }
#undef STAGE
#undef LOADA
#undef LOADB
#undef MFMAQ
#undef BARR
#undef LGKM0
#undef VM6
#undef PTAIL
#undef PEND
}

// ---------------- RMSNorm + RoPE on q,k (in place, [b][h][t][d]) -----------
__global__ __launch_bounds__(256) void norm_rope(
    unsigned short* __restrict__ Qp, unsigned short* __restrict__ Kp,
    const float* __restrict__ qw, const float* __restrict__ kw,
    const int* __restrict__ pos_ids)
{
    const int bid  = blockIdx.x;            // b*16384 + h*1024 + tg
    const int tg   = bid & 1023, h = (bid >> 10) & 15, b = bid >> 14;
    const int wave = threadIdx.x >> 6, lane = threadIdx.x & 63;
    const int t    = tg * 4 + wave;
    const long long rowbase = (((long long)(b * 16 + h)) * 4096 + t) * 128;
    const int pos = pos_ids[b * 4096 + t];
    const int d0  = lane * 2;

    float c0 = 1.f, s0 = 0.f, c1 = 1.f, s1 = 0.f;
    if (lane < 32) {
        float fj0 = (float)(d0 & 31), fj1 = (float)((d0 + 1) & 31);
        float if0 = exp2f(-fj0 * 0.4152410118609203f);  // log2(10000)/32
        float if1 = exp2f(-fj1 * 0.4152410118609203f);
        sincosf((float)pos * if0, &s0, &c0);
        sincosf((float)pos * if1, &s1, &c1);
    }
    const float w0q = qw[d0], w1q = qw[d0 + 1];
    const float w0k = kw[d0], w1k = kw[d0 + 1];

#pragma unroll
    for (int which = 0; which < 2; ++which) {
        unsigned short* P = which ? Kp : Qp;
        float w0 = which ? w0k : w0q, w1 = which ? w1k : w1q;
        unsigned u = *(const unsigned*)(P + rowbase + d0);
        float x0 = bf2f(u & 0xFFFF), x1 = bf2f(u >> 16);
        float ss = x0 * x0 + x1 * x1;
#pragma unroll
        for (int off = 32; off; off >>= 1) ss += __shfl_xor(ss, off);
        float r  = rsqrtf(ss * (1.0f / 128.0f) + 1e-6f);
        float xn0 = x0 * r * w0;
        float xn1 = x1 * r * w1;
        float p0 = __shfl_xor(xn0, 16);
        float p1 = __shfl_xor(xn1, 16);
        float y0, y1;
        if (d0 < 32)      { y0 = xn0 * c0 - p0 * s0; y1 = xn1 * c1 - p1 * s1; }
        else if (d0 < 64) { y0 = xn0 * c0 + p0 * s0; y1 = xn1 * c1 + p1 * s1; }
        else              { y0 = xn0; y1 = xn1; }
        if (which == 0) { y0 *= 0.08838834764831845f; y1 *= 0.08838834764831845f; }
        *(unsigned*)(P + rowbase + d0) =
            (unsigned)f2bf(y0) | ((unsigned)f2bf(y1) << 16);
    }
}

// ---------------- GLA phase A: per-chunk intra + update matrix -------------
__global__ __launch_bounds__(256) void gla_chunk(
    const unsigned short* __restrict__ Qp, const unsigned short* __restrict__ Kp,
    const unsigned short* __restrict__ Vp,
    unsigned short* __restrict__ Oint, unsigned short* __restrict__ Ubuf)
{
    __shared__ __attribute__((aligned(16))) unsigned short sK[64 * 136];
    __shared__ __attribute__((aligned(16))) unsigned short sVT[128 * 72];
    __shared__ __attribute__((aligned(16))) unsigned short sKT[128 * 72];
    __shared__ __attribute__((aligned(16))) unsigned short sAtt[64 * 72];

    const int bid = blockIdx.x;
    const int n = bid & 63, h = (bid >> 6) & 15, b = bid >> 10;
    const int tid = threadIdx.x, wave = tid >> 6, lane = tid & 63;
    const int quad = lane >> 4, lr = lane & 15;
    const float gl2 = -exp2f(-0.5f * (float)(h + 1)) * GSCALE * LOG2E;

    const long long rb = (((long long)(b * 16 + h)) * 4096 + (long long)n * 64) * 128;

    const int cS = wave * 16 + lr;
    const float qsc = exp2f(gl2 * (float)cS);
    bf16x8 qf[4];
#pragma unroll
    for (int ks = 0; ks < 4; ++ks) {
        union { uint4 v; unsigned short s[8]; } in, ou;
        in.v = *(const uint4*)(Qp + rb + cS * 128 + ks * 32 + quad * 8);
#pragma unroll
        for (int j = 0; j < 8; ++j) ou.s[j] = f2bf(bf2f(in.s[j]) * qsc);
        qf[ks] = *(bf16x8*)&ou;
    }
#pragma unroll
    for (int rr = 0; rr < 4; ++rr) {
        int idx = rr * 256 + tid;
        int c = idx >> 4, d8 = (idx & 15) << 3;
        *(uint4*)(sK + c * 136 + d8) = *(const uint4*)(Kp + rb + c * 128 + d8);
    }
#pragma unroll
    for (int rr = 0; rr < 4; ++rr) {
        int idx = rr * 256 + tid;
        int c = idx & 63, g8 = (idx >> 6) << 3;
        union { uint4 v; unsigned short s[8]; } vv, kk;
        vv.v = *(const uint4*)(Vp + rb + c * 128 + g8);
        kk.v = *(const uint4*)(Kp + rb + c * 128 + g8);
        float kdsc = exp2f(gl2 * (float)(64 - c));
#pragma unroll
        for (int j = 0; j < 8; ++j) {
            sVT[(g8 + j) * 72 + c] = vv.s[j];
            sKT[(g8 + j) * 72 + c] = f2bf(bf2f(kk.s[j]) * kdsc);
        }
    }
    __syncthreads();

    f32x4 aacc[4] = {};
#pragma unroll
    for (int nj = 0; nj < 4; ++nj)
#pragma unroll
        for (int ks = 0; ks < 4; ++ks) {
            bf16x8 bf = *(const bf16x8*)(sK + (nj * 16 + lr) * 136 + ks * 32 + quad * 8);
            aacc[nj] = MFMA16(qf[ks], bf, aacc[nj]);
        }
#pragma unroll
    for (int nj = 0; nj < 4; ++nj) {
        int c2 = nj * 16 + lr;
        float colf = exp2f(-gl2 * (float)c2);
#pragma unroll
        for (int r = 0; r < 4; ++r) {
            int c = wave * 16 + quad * 4 + r;
            sAtt[c * 72 + c2] = f2bf((c >= c2) ? aacc[nj][r] * colf : 0.0f);
        }
    }
    f32x4 Sacc[2][8] = {};
#pragma unroll
    for (int me = 0; me < 2; ++me)
#pragma unroll
        for (int ks = 0; ks < 2; ++ks) {
            bf16x8 af = *(const bf16x8*)(sVT + (wave * 32 + me * 16 + lr) * 72 + ks * 32 + quad * 8);
#pragma unroll
            for (int dj = 0; dj < 8; ++dj) {
                bf16x8 bf = *(const bf16x8*)(sKT + (dj * 16 + lr) * 72 + ks * 32 + quad * 8);
                Sacc[me][dj] = MFMA16(af, bf, Sacc[me][dj]);
            }
        }
    const long long ub = ((long long)((b * 16 + h) * 64 + n)) * 16384;
#pragma unroll
    for (int me = 0; me < 2; ++me)
#pragma unroll
        for (int r = 0; r < 4; ++r) {
            int e = wave * 32 + me * 16 + quad * 4 + r;
#pragma unroll
            for (int dj = 0; dj < 8; ++dj)
                Ubuf[ub + e * 128 + dj * 16 + lr] = f2bf(Sacc[me][dj][r]);
        }
    __syncthreads();

    f32x4 oacc[8] = {};
#pragma unroll
    for (int ks = 0; ks < 2; ++ks) {
        bf16x8 af = *(const bf16x8*)(sAtt + cS * 72 + ks * 32 + quad * 8);
#pragma unroll
        for (int ej = 0; ej < 8; ++ej) {
            bf16x8 bf = *(const bf16x8*)(sVT + (ej * 16 + lr) * 72 + ks * 32 + quad * 8);
            oacc[ej] = MFMA16(af, bf, oacc[ej]);
        }
    }
#pragma unroll
    for (int ej = 0; ej < 8; ++ej)
#pragma unroll
        for (int r = 0; r < 4; ++r) {
            int c = wave * 16 + quad * 4 + r;
            long long off = ((long long)(b * 4096 + n * 64 + c)) * 2048 + h * 128 + ej * 16 + lr;
            Oint[off] = f2bf(oacc[ej][r]);
        }
}

// ---------------- GLA phase B: chunk-level prefix scan ---------------------
__global__ __launch_bounds__(256) void gla_scan(
    const unsigned short* __restrict__ Ubuf, unsigned short* __restrict__ STbuf)
{
    const int bid = blockIdx.x;
    const int es = bid & 7, bh = bid >> 3;
    const int h = bh & 15;
    const float gl2 = -exp2f(-0.5f * (float)(h + 1)) * GSCALE * LOG2E;
    const float chd = exp2f(gl2 * 64.0f);
    const int tid = threadIdx.x;
    const long long base = (long long)bh * 64 * 16384 + es * 2048 + tid * 8;
    float st[8] = {};
    for (int n = 0; n < 64; ++n) {
        long long a = base + (long long)n * 16384;
        union { uint4 v; unsigned short s[8]; } u, o;
        u.v = *(const uint4*)(Ubuf + a);
#pragma unroll
        for (int j = 0; j < 8; ++j) o.s[j] = f2bf(st[j]);
        *(uint4*)(STbuf + a) = o.v;
#pragma unroll
        for (int j = 0; j < 8; ++j) st[j] = st[j] * chd + bf2f(u.s[j]);
    }
}

// ---------------- GLA phase C: inter + group-RMSNorm * gate ----------------
__global__ __launch_bounds__(256) void gla_inter(
    const unsigned short* __restrict__ Qp, const unsigned short* __restrict__ STbuf,
    unsigned short* __restrict__ Ob, const unsigned short* __restrict__ Gb,
    const float* __restrict__ W)
{
    __shared__ __attribute__((aligned(16))) unsigned short sST[128 * 136];
    const int bid = blockIdx.x;
    const int n = bid & 63, h = (bid >> 6) & 15, b = bid >> 10;
    const int tid = threadIdx.x, wave = tid >> 6, lane = tid & 63;
    const int quad = lane >> 4, lr = lane & 15;
    const float gl2 = -exp2f(-0.5f * (float)(h + 1)) * GSCALE * LOG2E;
    const long long rb = (((long long)(b * 16 + h)) * 4096 + (long long)n * 64) * 128;
    const long long stb = ((long long)((b * 16 + h) * 64 + n)) * 16384;

#pragma unroll
    for (int rr = 0; rr < 8; ++rr) {
        int idx = rr * 256 + tid;
        int row = idx >> 4, d8 = (idx & 15) << 3;
        *(uint4*)(sST + row * 136 + d8) = *(const uint4*)(STbuf + stb + row * 128 + d8);
    }
    const int cS = wave * 16 + lr;
    const float qsc = exp2f(gl2 * (float)cS);
    bf16x8 qf[4];
#pragma unroll
    for (int ks = 0; ks < 4; ++ks) {
        union { uint4 v; unsigned short s[8]; } in, ou;
        in.v = *(const uint4*)(Qp + rb + cS * 128 + ks * 32 + quad * 8);
#pragma unroll
        for (int j = 0; j < 8; ++j) ou.s[j] = f2bf(bf2f(in.s[j]) * qsc);
        qf[ks] = *(bf16x8*)&ou;
    }
    __syncthreads();

    f32x4 oacc[8] = {};
#pragma unroll
    for (int ks = 0; ks < 4; ++ks)
#pragma unroll
        for (int ej = 0; ej < 8; ++ej) {
            bf16x8 bf = *(const bf16x8*)(sST + (ej * 16 + lr) * 136 + ks * 32 + quad * 8);
            oacc[ej] = MFMA16(qf[ks], bf, oacc[ej]);
        }

    float w[8];
#pragma unroll
    for (int ej = 0; ej < 8; ++ej) w[ej] = W[h * 128 + ej * 16 + lr];

    float ss[4] = {};
#pragma unroll
    for (int r = 0; r < 4; ++r) {
        int c = wave * 16 + quad * 4 + r;
        long long off = ((long long)(b * 4096 + n * 64 + c)) * 2048 + h * 128;
#pragma unroll
        for (int ej = 0; ej < 8; ++ej) {
            float v = oacc[ej][r] + bf2f(Ob[off + ej * 16 + lr]);
            oacc[ej][r] = v;
            ss[r] += v * v;
        }
    }
#pragma unroll
    for (int r = 0; r < 4; ++r) {
#pragma unroll
        for (int o2 = 1; o2 < 16; o2 <<= 1) ss[r] += __shfl_xor(ss[r], o2);
        float rn = rsqrtf(ss[r] * (1.0f / 128.0f) + 1e-6f);
        int c = wave * 16 + quad * 4 + r;
        long long off = ((long long)(b * 4096 + n * 64 + c)) * 2048 + h * 128;
#pragma unroll
        for (int ej = 0; ej < 8; ++ej) {
            float g = bf2f(Gb[off + ej * 16 + lr]);
            Ob[off + ej * 16 + lr] = f2bf(oacc[ej][r] * rn * w[ej] * g);
        }
    }
}

// ---------------- launcher ----------------
extern "C" void kernel_launch(void* const* d_in, const int* in_sizes, int n_in,
                              void* d_out, int out_size, void* d_ws, size_t ws_size,
                              hipStream_t stream)
{
    const float* hid   = (const float*)d_in[0];
    const float* w_qkv = (const float*)d_in[1];
    const float* q_ln  = (const float*)d_in[2];
    const float* k_ln  = (const float*)d_in[3];
    const float* g_nw  = (const float*)d_in[4];
    const float* w_g   = (const float*)d_in[5];
    const float* w_d   = (const float*)d_in[6];
    const int*   pos   = (const int*)d_in[7];

    const size_t PLANE = (size_t)2 * 16 * 4096 * 128;  // 16.78M elems
    unsigned short* Qp    = (unsigned short*)d_ws;
    unsigned short* Kp    = Qp + PLANE;
    unsigned short* Vp    = Kp + PLANE;
    unsigned short* Ob    = Vp + PLANE;
    unsigned short* Gb    = Ob + PLANE;
    unsigned short* hidb  = Gb + PLANE;                  // 8192*2048
    unsigned short* wqkvb = hidb + (size_t)8192 * 2048;  // 6144*2048  (qkv ‖ gate)
    unsigned short* wgb   = wqkvb + (size_t)6144 * 2048; // 2048*2048  (contiguous!)
    unsigned short* wdb   = wgb + (size_t)2048 * 2048;   // 2048*2048
    // aliases (lifetimes disjoint by stream order):
    unsigned short* Ubuf  = hidb;  // 33.55M elems == hidb+wqkvb+wgb exactly
    unsigned short* STbuf = Kp;    // 33.55M elems == Kp+Vp

    dim3 blk(256);
    const int c0 = 8192 * 2048 / 4;                 // hid
    const int c1 = c0 + 6144 * 2048 / 4;            // w_qkv
    const int c2 = c1 + 2048 * 2048 / 4;            // w_g
    const int n4 = c2 + 2048 * 2048 / 4;            // w_d
    cvt4_f32_bf16<<<(n4 + 255) / 256, blk, 0, stream>>>(
        hid, w_qkv, w_g, w_d, hidb, c0, c1, c2, n4);

    // merged QKV+gate projection: B = [w_qkv ; w_g], N=8192 (256² 8-phase)
    gemm256<0><<<dim3(32, 32), dim3(512), 0, stream>>>(
        hidb, wqkvb, nullptr, Qp, Kp, Vp, Gb, 8192, 8192, 2048);
    // q/k rmsnorm + rope (+ q * D^-0.5), in place
    norm_rope<<<32768, blk, 0, stream>>>(Qp, Kp, q_ln, k_ln, pos);
    // GLA: per-chunk work (parallel) -> scan (cheap) -> inter + norm*gate
    gla_chunk<<<2048, blk, 0, stream>>>(Qp, Kp, Vp, Ob, Ubuf);
    gla_scan<<<256, blk, 0, stream>>>(Ubuf, STbuf);
    gla_inter<<<2048, blk, 0, stream>>>(Qp, STbuf, Ob, Gb, g_nw);
    // output projection -> f32 d_out (256² 8-phase)
    gemm256<2><<<dim3(8, 32), dim3(512), 0, stream>>>(
        Ob, wdb, d_out, nullptr, nullptr, nullptr, nullptr, 8192, 2048, 2048);
}

// Round 2
// 634.935 us; speedup vs baseline: 1.1050x; 1.0332x over previous
//
#include <hip/hip_runtime.h>
#include <math.h>

// ---------------- common helpers ----------------
typedef short bf16x8 __attribute__((ext_vector_type(8)));
typedef float f32x4 __attribute__((ext_vector_type(4)));

#define LOG2E 1.4426950408889634f
#define GSCALE 0.6451712903225806f   /* 1 - 11/31 + 1e-5 */

__device__ __forceinline__ float bf2f(unsigned short h) {
    union { unsigned u; float f; } v; v.u = ((unsigned)h) << 16; return v.f;
}
__device__ __forceinline__ unsigned short f2bf(float f) {
    union { float f; unsigned u; } v; v.f = f;
    unsigned r = v.u + 0x7FFFu + ((v.u >> 16) & 1u);
    return (unsigned short)(r >> 16);
}

#define GLD16(lds, g)                                                          \
    __builtin_amdgcn_global_load_lds(                                          \
        (const __attribute__((address_space(1))) void*)(g),                    \
        (__attribute__((address_space(3))) void*)(lds), 16, 0, 0)

#define MFMA16(a, b, c) __builtin_amdgcn_mfma_f32_16x16x32_bf16(a, b, c, 0, 0, 0)

// ---------------- fused f32 -> bf16 conversion (4 srcs, contiguous dst) ----
struct us4 { unsigned short a, b, c, d; };
__global__ __launch_bounds__(256) void cvt4_f32_bf16(
    const float* __restrict__ s0, const float* __restrict__ s1,
    const float* __restrict__ s2, const float* __restrict__ s3,
    unsigned short* __restrict__ dst, int c0, int c1, int c2, int n4)
{
    int i = blockIdx.x * 256 + threadIdx.x;
    if (i >= n4) return;
    const float* s; int off;
    if (i < c0)      { s = s0; off = i; }
    else if (i < c1) { s = s1; off = i - c0; }
    else if (i < c2) { s = s2; off = i - c1; }
    else             { s = s3; off = i - c2; }
    float4 v = ((const float4*)s)[off];
    us4 o = { f2bf(v.x), f2bf(v.y), f2bf(v.z), f2bf(v.w) };
    ((us4*)dst)[i] = o;
}

// ---------------- 256x256 8-phase GEMM: C = A @ Bt^T (bf16, f32 acc) -------
// 8 waves (2M x 4N), per-wave 128x64 output, BK=64, double-buffered 128 KiB
// LDS, global_load_lds staging with XOR-8 source pre-swizzle (linear LDS
// dest, swizzled ds_read -> conflict-free). One half-tile STAGE per phase
// (P2 none, P8 two); counted vmcnt(4)@P4 / vmcnt(6)@P8. Every MFMA cluster
// fenced by sched_barrier(0) on BOTH sides so hipcc cannot hoist/sink the
// register-only MFMAs across the asm barriers (rule #18/#19).
// EPI 0: col<6144 -> scatter Q/K/V [b][h][t][d]; col>=6144 -> sigmoid -> Gb
// EPI 2: plain f32 -> C
template <int EPI>
__global__ __launch_bounds__(512, 2) void gemm256(
    const unsigned short* __restrict__ A, const unsigned short* __restrict__ Bt,
    void* __restrict__ Cv,
    unsigned short* __restrict__ Qp, unsigned short* __restrict__ Kp,
    unsigned short* __restrict__ Vp, unsigned short* __restrict__ Gb,
    int M, int N, int K)
{
    __shared__ __attribute__((aligned(16))) unsigned short lA[2][16384];
    __shared__ __attribute__((aligned(16))) unsigned short lB[2][16384];

    const int tid  = threadIdx.x;
    const int lane = tid & 63, wave = tid >> 6;
    const int quad = lane >> 4, lr = lane & 15;
    const int wm   = (wave >> 2) * 128;   // 0 / 128
    const int wn   = (wave & 3) * 64;     // 0 / 64 / 128 / 192
    const int lsw  = lr & 7;

    // XCD-aware bijective swizzle, column-major within each XCD chunk:
    // chunk j walks bm fastest -> concurrent working set per XCD =
    // RPC A-panels + (CUs/RPC) B-panels (~12 MB) instead of 32 B-panels.
    // Requires gridDim.y % 8 == 0 (both launches: gridDim.y = 32).
    const int lin = (int)(blockIdx.y * gridDim.x + blockIdx.x);
    const int xcd = lin & 7, j = lin >> 3;
    const int RPC = (int)gridDim.y >> 3;
    const int bm  = xcd * RPC + (j % RPC);
    const int bn  = j / RPC;

    const unsigned short* Ab = A  + (long long)bm * 256 * K;
    const unsigned short* Bb = Bt + (long long)bn * 256 * K;

    // staging geometry: half-tile = 128 rows x 64 cols bf16 = 16 KiB
    // = 2 sweeps x (512 thr x 16B). LDS dest linear; global src pre-swizzled
    // so LDS slot g of row r holds global group g^(r&7).
    const int c0r = tid, c1r = 512 + tid;
    const int row0 = c0r >> 3, row1 = c1r >> 3;
    const long long ga0 = (long long)row0 * K + ((c0r & 7) ^ (row0 & 7)) * 8;
    const long long ga1 = (long long)row1 * K + ((c1r & 7) ^ (row1 & 7)) * 8;
    const long long HK  = (long long)128 * K;
    const int l0 = c0r * 8, l1 = c1r * 8;

#define STAGE(ldsb, gb, half, kt)                                              \
    do {                                                                       \
        GLD16((ldsb) + (half) * 8192 + l0, (gb) + (half) * HK + (kt) + ga0);   \
        GLD16((ldsb) + (half) * 8192 + l1, (gb) + (half) * HK + (kt) + ga1);   \
    } while (0)

    f32x4 acc[8][4] = {};
    bf16x8 a[4][2], blo[2][2], bhi[2][2];

#define LOADA(buf, base)                                                       \
    _Pragma("unroll") for (int i = 0; i < 4; ++i)                              \
    _Pragma("unroll") for (int s = 0; s < 2; ++s)                              \
        a[i][s] = *(const bf16x8*)((buf) + ((base) + i * 16 + lr) * 64 +       \
                                   (((s * 4 + quad) ^ lsw) * 8));
#define LOADB(dst, buf, base)                                                  \
    _Pragma("unroll") for (int j2 = 0; j2 < 2; ++j2)                           \
    _Pragma("unroll") for (int s = 0; s < 2; ++s)                              \
        dst[j2][s] = *(const bf16x8*)((buf) + ((base) + j2 * 16 + lr) * 64 +   \
                                      (((s * 4 + quad) ^ lsw) * 8));
#define MFMAQ(MQ, NQ, BV)                                                      \
    _Pragma("unroll") for (int i = 0; i < 4; ++i)                              \
    _Pragma("unroll") for (int j2 = 0; j2 < 2; ++j2)                           \
    _Pragma("unroll") for (int s = 0; s < 2; ++s)                              \
        acc[(MQ) * 4 + i][(NQ) * 2 + j2] =                                     \
            MFMA16(a[i][s], BV[j2][s], acc[(MQ) * 4 + i][(NQ) * 2 + j2]);

#define BARR()  asm volatile("s_barrier" ::: "memory")
#define LGKM0() asm volatile("s_waitcnt lgkmcnt(0)" ::: "memory")
#define VM4()   asm volatile("s_waitcnt vmcnt(4)" ::: "memory")
#define VM6()   asm volatile("s_waitcnt vmcnt(6)" ::: "memory")
#define SBAR()  __builtin_amdgcn_sched_barrier(0)
#define PBEG()  do { BARR(); LGKM0(); SBAR();                                  \
                     __builtin_amdgcn_s_setprio(1); } while (0)
#define PBEGW(W) do { W(); BARR(); SBAR();                                     \
                     __builtin_amdgcn_s_setprio(1); } while (0)
#define PEND()  do { SBAR(); __builtin_amdgcn_s_setprio(0); BARR(); } while (0)

    // ---- prologue: tile0 {A0,A1,B0,B1} + tile1 {B0,B1,A0}; A1(1) at P1 ----
    STAGE(lA[0], Ab, 0, 0); STAGE(lA[0], Ab, 1, 0);
    STAGE(lB[0], Bb, 0, 0); STAGE(lB[0], Bb, 1, 0);
    STAGE(lB[1], Bb, 0, 64); STAGE(lB[1], Bb, 1, 64);
    STAGE(lA[1], Ab, 0, 64);
    VM6();          // tile0's 8 loads complete; tile1's 6 remain in flight
    BARR();

    const int NT = K >> 6;
    for (int it = 0; it < (NT >> 1); ++it) {
        const int v   = 2 * it + 1;
        const int kn0 = (2 * it + 2 < NT) ? (2 * it + 2) * 64 : 0; // clamp tail
        const int kn1 = (2 * it + 3 < NT) ? (2 * it + 3) * 64 : 0;
        // ---- P1: Q(lo,lo) of tile u; issue A1(v) ----
        LOADA(lA[0], wm); LOADB(blo, lB[0], wn);
        STAGE(lA[1], Ab, 1, v * 64);
        PBEG(); MFMAQ(0, 0, blo); PEND();
        // ---- P2: Q(lo,hi) ----
        LOADB(bhi, lB[0], wn + 32);
        PBEG(); MFMAQ(0, 1, bhi); PEND();
        // ---- P3: Q(hi,hi); issue B0(u+2) (buf0 B reads ended P2) ----
        LOADA(lA[0], wm + 64);
        STAGE(lB[0], Bb, 0, kn0);
        PBEG(); MFMAQ(1, 1, bhi); PEND();
        // ---- P4: Q(hi,lo); issue B1(u+2); vmcnt(4) -> tile v fully ready --
        STAGE(lB[0], Bb, 1, kn0);
        PBEGW(VM4); MFMAQ(1, 0, blo); PEND();
        // ---- P5: Q(lo,lo) of tile v; issue A0(u+2) (buf0 A reads done P3) --
        LOADA(lA[1], wm); LOADB(blo, lB[1], wn);
        STAGE(lA[0], Ab, 0, kn0);
        PBEG(); MFMAQ(0, 0, blo); PEND();
        // ---- P6: Q(lo,hi); issue A1(u+2) ----
        LOADB(bhi, lB[1], wn + 32);
        STAGE(lA[0], Ab, 1, kn0);
        PBEG(); MFMAQ(0, 1, bhi); PEND();
        // ---- P7: Q(hi,hi); issue B0(v+2) ----
        LOADA(lA[1], wm + 64);
        STAGE(lB[1], Bb, 0, kn1);
        PBEG(); MFMAQ(1, 1, bhi); PEND();
        // ---- P8: Q(hi,lo); issue B1,A0(v+2); vmcnt(6) -> tile u+2 ready ---
        STAGE(lB[1], Bb, 1, kn1); STAGE(lA[1], Ab, 0, kn1);
        PBEGW(VM6); MFMAQ(1, 0, blo); PEND();
    }
    asm volatile("s_waitcnt vmcnt(0)" ::: "memory");  // drain before LDS dealloc

    // ---- epilogue ----
#pragma unroll
    for (int i = 0; i < 8; ++i)
#pragma unroll
        for (int j2 = 0; j2 < 4; ++j2)
#pragma unroll
            for (int r = 0; r < 4; ++r) {
                int row = bm * 256 + wm + i * 16 + quad * 4 + r;
                int col = bn * 256 + wn + j2 * 16 + lr;
                float vv = acc[i][j2][r];
                if (EPI == 0) {
                    if (col < 6144) {
                        int tens = col >> 11, h = (col >> 7) & 15, e = col & 127;
                        int b = row >> 12, t = row & 4095;
                        long long dst = (((long long)(b * 16 + h)) * 4096 + t) * 128 + e;
                        unsigned short* P = (tens == 0) ? Qp : ((tens == 1) ? Kp : Vp);
                        P[dst] = f2bf(vv);
                    } else {
                        vv = 1.0f / (1.0f + __expf(-vv));
                        Gb[(long long)row * 2048 + (col - 6144)] = f2bf(vv);
                    }
                } else {
                    ((float*)Cv)[(long long)row * N + col] = vv;
                }
            }
#undef STAGE
#undef LOADA
#undef LOADB
#undef MFMAQ
#undef BARR
#undef LGKM0
#undef VM4
#undef VM6
#undef SBAR
#undef PBEG
#undef PBEGW
#undef PEND
}

// ---------------- RMSNorm + RoPE on q,k (in place, [b][h][t][d]) -----------
__global__ __launch_bounds__(256) void norm_rope(
    unsigned short* __restrict__ Qp, unsigned short* __restrict__ Kp,
    const float* __restrict__ qw, const float* __restrict__ kw,
    const int* __restrict__ pos_ids)
{
    const int bid  = blockIdx.x;            // b*16384 + h*1024 + tg
    const int tg   = bid & 1023, h = (bid >> 10) & 15, b = bid >> 14;
    const int wave = threadIdx.x >> 6, lane = threadIdx.x & 63;
    const int t    = tg * 4 + wave;
    const long long rowbase = (((long long)(b * 16 + h)) * 4096 + t) * 128;
    const int pos = pos_ids[b * 4096 + t];
    const int d0  = lane * 2;

    float c0 = 1.f, s0 = 0.f, c1 = 1.f, s1 = 0.f;
    if (lane < 32) {
        float fj0 = (float)(d0 & 31), fj1 = (float)((d0 + 1) & 31);
        float if0 = exp2f(-fj0 * 0.4152410118609203f);  // log2(10000)/32
        float if1 = exp2f(-fj1 * 0.4152410118609203f);
        sincosf((float)pos * if0, &s0, &c0);
        sincosf((float)pos * if1, &s1, &c1);
    }
    const float w0q = qw[d0], w1q = qw[d0 + 1];
    const float w0k = kw[d0], w1k = kw[d0 + 1];

#pragma unroll
    for (int which = 0; which < 2; ++which) {
        unsigned short* P = which ? Kp : Qp;
        float w0 = which ? w0k : w0q, w1 = which ? w1k : w1q;
        unsigned u = *(const unsigned*)(P + rowbase + d0);
        float x0 = bf2f(u & 0xFFFF), x1 = bf2f(u >> 16);
        float ss = x0 * x0 + x1 * x1;
#pragma unroll
        for (int off = 32; off; off >>= 1) ss += __shfl_xor(ss, off);
        float r  = rsqrtf(ss * (1.0f / 128.0f) + 1e-6f);
        float xn0 = x0 * r * w0;
        float xn1 = x1 * r * w1;
        float p0 = __shfl_xor(xn0, 16);
        float p1 = __shfl_xor(xn1, 16);
        float y0, y1;
        if (d0 < 32)      { y0 = xn0 * c0 - p0 * s0; y1 = xn1 * c1 - p1 * s1; }
        else if (d0 < 64) { y0 = xn0 * c0 + p0 * s0; y1 = xn1 * c1 + p1 * s1; }
        else              { y0 = xn0; y1 = xn1; }
        if (which == 0) { y0 *= 0.08838834764831845f; y1 *= 0.08838834764831845f; }
        *(unsigned*)(P + rowbase + d0) =
            (unsigned)f2bf(y0) | ((unsigned)f2bf(y1) << 16);
    }
}

// ---------------- GLA phase A: per-chunk intra + update matrix -------------
__global__ __launch_bounds__(256) void gla_chunk(
    const unsigned short* __restrict__ Qp, const unsigned short* __restrict__ Kp,
    const unsigned short* __restrict__ Vp,
    unsigned short* __restrict__ Oint, unsigned short* __restrict__ Ubuf)
{
    __shared__ __attribute__((aligned(16))) unsigned short sK[64 * 136];
    __shared__ __attribute__((aligned(16))) unsigned short sVT[128 * 72];
    __shared__ __attribute__((aligned(16))) unsigned short sKT[128 * 72];
    __shared__ __attribute__((aligned(16))) unsigned short sAtt[64 * 72];

    const int bid = blockIdx.x;
    const int n = bid & 63, h = (bid >> 6) & 15, b = bid >> 10;
    const int tid = threadIdx.x, wave = tid >> 6, lane = tid & 63;
    const int quad = lane >> 4, lr = lane & 15;
    const float gl2 = -exp2f(-0.5f * (float)(h + 1)) * GSCALE * LOG2E;

    const long long rb = (((long long)(b * 16 + h)) * 4096 + (long long)n * 64) * 128;

    const int cS = wave * 16 + lr;
    const float qsc = exp2f(gl2 * (float)cS);
    bf16x8 qf[4];
#pragma unroll
    for (int ks = 0; ks < 4; ++ks) {
        union { uint4 v; unsigned short s[8]; } in, ou;
        in.v = *(const uint4*)(Qp + rb + cS * 128 + ks * 32 + quad * 8);
#pragma unroll
        for (int j = 0; j < 8; ++j) ou.s[j] = f2bf(bf2f(in.s[j]) * qsc);
        qf[ks] = *(bf16x8*)&ou;
    }
#pragma unroll
    for (int rr = 0; rr < 4; ++rr) {
        int idx = rr * 256 + tid;
        int c = idx >> 4, d8 = (idx & 15) << 3;
        *(uint4*)(sK + c * 136 + d8) = *(const uint4*)(Kp + rb + c * 128 + d8);
    }
#pragma unroll
    for (int rr = 0; rr < 4; ++rr) {
        int idx = rr * 256 + tid;
        int c = idx & 63, g8 = (idx >> 6) << 3;
        union { uint4 v; unsigned short s[8]; } vv, kk;
        vv.v = *(const uint4*)(Vp + rb + c * 128 + g8);
        kk.v = *(const uint4*)(Kp + rb + c * 128 + g8);
        float kdsc = exp2f(gl2 * (float)(64 - c));
#pragma unroll
        for (int j = 0; j < 8; ++j) {
            sVT[(g8 + j) * 72 + c] = vv.s[j];
            sKT[(g8 + j) * 72 + c] = f2bf(bf2f(kk.s[j]) * kdsc);
        }
    }
    __syncthreads();

    f32x4 aacc[4] = {};
#pragma unroll
    for (int nj = 0; nj < 4; ++nj)
#pragma unroll
        for (int ks = 0; ks < 4; ++ks) {
            bf16x8 bf = *(const bf16x8*)(sK + (nj * 16 + lr) * 136 + ks * 32 + quad * 8);
            aacc[nj] = MFMA16(qf[ks], bf, aacc[nj]);
        }
#pragma unroll
    for (int nj = 0; nj < 4; ++nj) {
        int c2 = nj * 16 + lr;
        float colf = exp2f(-gl2 * (float)c2);
#pragma unroll
        for (int r = 0; r < 4; ++r) {
            int c = wave * 16 + quad * 4 + r;
            sAtt[c * 72 + c2] = f2bf((c >= c2) ? aacc[nj][r] * colf : 0.0f);
        }
    }
    f32x4 Sacc[2][8] = {};
#pragma unroll
    for (int me = 0; me < 2; ++me)
#pragma unroll
        for (int ks = 0; ks < 2; ++ks) {
            bf16x8 af = *(const bf16x8*)(sVT + (wave * 32 + me * 16 + lr) * 72 + ks * 32 + quad * 8);
#pragma unroll
            for (int dj = 0; dj < 8; ++dj) {
                bf16x8 bf = *(const bf16x8*)(sKT + (dj * 16 + lr) * 72 + ks * 32 + quad * 8);
                Sacc[me][dj] = MFMA16(af, bf, Sacc[me][dj]);
            }
        }
    const long long ub = ((long long)((b * 16 + h) * 64 + n)) * 16384;
#pragma unroll
    for (int me = 0; me < 2; ++me)
#pragma unroll
        for (int r = 0; r < 4; ++r) {
            int e = wave * 32 + me * 16 + quad * 4 + r;
#pragma unroll
            for (int dj = 0; dj < 8; ++dj)
                Ubuf[ub + e * 128 + dj * 16 + lr] = f2bf(Sacc[me][dj][r]);
        }
    __syncthreads();

    f32x4 oacc[8] = {};
#pragma unroll
    for (int ks = 0; ks < 2; ++ks) {
        bf16x8 af = *(const bf16x8*)(sAtt + cS * 72 + ks * 32 + quad * 8);
#pragma unroll
        for (int ej = 0; ej < 8; ++ej) {
            bf16x8 bf = *(const bf16x8*)(sVT + (ej * 16 + lr) * 72 + ks * 32 + quad * 8);
            oacc[ej] = MFMA16(af, bf, oacc[ej]);
        }
    }
#pragma unroll
    for (int ej = 0; ej < 8; ++ej)
#pragma unroll
        for (int r = 0; r < 4; ++r) {
            int c = wave * 16 + quad * 4 + r;
            long long off = ((long long)(b * 4096 + n * 64 + c)) * 2048 + h * 128 + ej * 16 + lr;
            Oint[off] = f2bf(oacc[ej][r]);
        }
}

// ---------------- GLA phase B: chunk-level prefix scan ---------------------
__global__ __launch_bounds__(256) void gla_scan(
    const unsigned short* __restrict__ Ubuf, unsigned short* __restrict__ STbuf)
{
    const int bid = blockIdx.x;
    const int es = bid & 7, bh = bid >> 3;
    const int h = bh & 15;
    const float gl2 = -exp2f(-0.5f * (float)(h + 1)) * GSCALE * LOG2E;
    const float chd = exp2f(gl2 * 64.0f);
    const int tid = threadIdx.x;
    const long long base = (long long)bh * 64 * 16384 + es * 2048 + tid * 8;
    float st[8] = {};
    for (int n = 0; n < 64; ++n) {
        long long a = base + (long long)n * 16384;
        union { uint4 v; unsigned short s[8]; } u, o;
        u.v = *(const uint4*)(Ubuf + a);
#pragma unroll
        for (int j = 0; j < 8; ++j) o.s[j] = f2bf(st[j]);
        *(uint4*)(STbuf + a) = o.v;
#pragma unroll
        for (int j = 0; j < 8; ++j) st[j] = st[j] * chd + bf2f(u.s[j]);
    }
}

// ---------------- GLA phase C: inter + group-RMSNorm * gate ----------------
__global__ __launch_bounds__(256) void gla_inter(
    const unsigned short* __restrict__ Qp, const unsigned short* __restrict__ STbuf,
    unsigned short* __restrict__ Ob, const unsigned short* __restrict__ Gb,
    const float* __restrict__ W)
{
    __shared__ __attribute__((aligned(16))) unsigned short sST[128 * 136];
    const int bid = blockIdx.x;
    const int n = bid & 63, h = (bid >> 6) & 15, b = bid >> 10;
    const int tid = threadIdx.x, wave = tid >> 6, lane = tid & 63;
    const int quad = lane >> 4, lr = lane & 15;
    const float gl2 = -exp2f(-0.5f * (float)(h + 1)) * GSCALE * LOG2E;
    const long long rb = (((long long)(b * 16 + h)) * 4096 + (long long)n * 64) * 128;
    const long long stb = ((long long)((b * 16 + h) * 64 + n)) * 16384;

#pragma unroll
    for (int rr = 0; rr < 8; ++rr) {
        int idx = rr * 256 + tid;
        int row = idx >> 4, d8 = (idx & 15) << 3;
        *(uint4*)(sST + row * 136 + d8) = *(const uint4*)(STbuf + stb + row * 128 + d8);
    }
    const int cS = wave * 16 + lr;
    const float qsc = exp2f(gl2 * (float)cS);
    bf16x8 qf[4];
#pragma unroll
    for (int ks = 0; ks < 4; ++ks) {
        union { uint4 v; unsigned short s[8]; } in, ou;
        in.v = *(const uint4*)(Qp + rb + cS * 128 + ks * 32 + quad * 8);
#pragma unroll
        for (int j = 0; j < 8; ++j) ou.s[j] = f2bf(bf2f(in.s[j]) * qsc);
        qf[ks] = *(bf16x8*)&ou;
    }
    __syncthreads();

    f32x4 oacc[8] = {};
#pragma unroll
    for (int ks = 0; ks < 4; ++ks)
#pragma unroll
        for (int ej = 0; ej < 8; ++ej) {
            bf16x8 bf = *(const bf16x8*)(sST + (ej * 16 + lr) * 136 + ks * 32 + quad * 8);
            oacc[ej] = MFMA16(qf[ks], bf, oacc[ej]);
        }

    float w[8];
#pragma unroll
    for (int ej = 0; ej < 8; ++ej) w[ej] = W[h * 128 + ej * 16 + lr];

    float ss[4] = {};
#pragma unroll
    for (int r = 0; r < 4; ++r) {
        int c = wave * 16 + quad * 4 + r;
        long long off = ((long long)(b * 4096 + n * 64 + c)) * 2048 + h * 128;
#pragma unroll
        for (int ej = 0; ej < 8; ++ej) {
            float v = oacc[ej][r] + bf2f(Ob[off + ej * 16 + lr]);
            oacc[ej][r] = v;
            ss[r] += v * v;
        }
    }
#pragma unroll
    for (int r = 0; r < 4; ++r) {
#pragma unroll
        for (int o2 = 1; o2 < 16; o2 <<= 1) ss[r] += __shfl_xor(ss[r], o2);
        float rn = rsqrtf(ss[r] * (1.0f / 128.0f) + 1e-6f);
        int c = wave * 16 + quad * 4 + r;
        long long off = ((long long)(b * 4096 + n * 64 + c)) * 2048 + h * 128;
#pragma unroll
        for (int ej = 0; ej < 8; ++ej) {
            float g = bf2f(Gb[off + ej * 16 + lr]);
            Ob[off + ej * 16 + lr] = f2bf(oacc[ej][r] * rn * w[ej] * g);
        }
    }
}

// ---------------- launcher ----------------
extern "C" void kernel_launch(void* const* d_in, const int* in_sizes, int n_in,
                              void* d_out, int out_size, void* d_ws, size_t ws_size,
                              hipStream_t stream)
{
    const float* hid   = (const float*)d_in[0];
    const float* w_qkv = (const float*)d_in[1];
    const float* q_ln  = (const float*)d_in[2];
    const float* k_ln  = (const float*)d_in[3];
    const float* g_nw  = (const float*)d_in[4];
    const float* w_g   = (const float*)d_in[5];
    const float* w_d   = (const float*)d_in[6];
    const int*   pos   = (const int*)d_in[7];

    const size_t PLANE = (size_t)2 * 16 * 4096 * 128;  // 16.78M elems
    unsigned short* Qp    = (unsigned short*)d_ws;
    unsigned short* Kp    = Qp + PLANE;
    unsigned short* Vp    = Kp + PLANE;
    unsigned short* Ob    = Vp + PLANE;
    unsigned short* Gb    = Ob + PLANE;
    unsigned short* hidb  = Gb + PLANE;                  // 8192*2048
    unsigned short* wqkvb = hidb + (size_t)8192 * 2048;  // 6144*2048  (qkv ‖ gate)
    unsigned short* wgb   = wqkvb + (size_t)6144 * 2048; // 2048*2048  (contiguous!)
    unsigned short* wdb   = wgb + (size_t)2048 * 2048;   // 2048*2048
    // aliases (lifetimes disjoint by stream order):
    unsigned short* Ubuf  = hidb;  // 33.55M elems == hidb+wqkvb+wgb exactly
    unsigned short* STbuf = Kp;    // 33.55M elems == Kp+Vp

    dim3 blk(256);
    const int c0 = 8192 * 2048 / 4;                 // hid
    const int c1 = c0 + 6144 * 2048 / 4;            // w_qkv
    const int c2 = c1 + 2048 * 2048 / 4;            // w_g
    const int n4 = c2 + 2048 * 2048 / 4;            // w_d
    cvt4_f32_bf16<<<(n4 + 255) / 256, blk, 0, stream>>>(
        hid, w_qkv, w_g, w_d, hidb, c0, c1, c2, n4);

    // merged QKV+gate projection: B = [w_qkv ; w_g], N=8192 (256² 8-phase)
    gemm256<0><<<dim3(32, 32), dim3(512), 0, stream>>>(
        hidb, wqkvb, nullptr, Qp, Kp, Vp, Gb, 8192, 8192, 2048);
    // q/k rmsnorm + rope (+ q * D^-0.5), in place
    norm_rope<<<32768, blk, 0, stream>>>(Qp, Kp, q_ln, k_ln, pos);
    // GLA: per-chunk work (parallel) -> scan (cheap) -> inter + norm*gate
    gla_chunk<<<2048, blk, 0, stream>>>(Qp, Kp, Vp, Ob, Ubuf);
    gla_scan<<<256, blk, 0, stream>>>(Ubuf, STbuf);
    gla_inter<<<2048, blk, 0, stream>>>(Qp, STbuf, Ob, Gb, g_nw);
    // output projection -> f32 d_out (256² 8-phase)
    gemm256<2><<<dim3(8, 32), dim3(512), 0, stream>>>(
        Ob, wdb, d_out, nullptr, nullptr, nullptr, nullptr, 8192, 2048, 2048);
}

// Round 3
// 626.119 us; speedup vs baseline: 1.1206x; 1.0141x over previous
//
#include <hip/hip_runtime.h>
#include <math.h>

// ---------------- common helpers ----------------
typedef short bf16x8 __attribute__((ext_vector_type(8)));
typedef float f32x4 __attribute__((ext_vector_type(4)));

#define LOG2E 1.4426950408889634f
#define GSCALE 0.6451712903225806f   /* 1 - 11/31 + 1e-5 */

__device__ __forceinline__ float bf2f(unsigned short h) {
    union { unsigned u; float f; } v; v.u = ((unsigned)h) << 16; return v.f;
}
__device__ __forceinline__ unsigned short f2bf(float f) {
    union { float f; unsigned u; } v; v.f = f;
    unsigned r = v.u + 0x7FFFu + ((v.u >> 16) & 1u);
    return (unsigned short)(r >> 16);
}

#define GLD16(lds, g)                                                          \
    __builtin_amdgcn_global_load_lds(                                          \
        (const __attribute__((address_space(1))) void*)(g),                    \
        (__attribute__((address_space(3))) void*)(lds), 16, 0, 0)

#define MFMA16(a, b, c) __builtin_amdgcn_mfma_f32_16x16x32_bf16(a, b, c, 0, 0, 0)

// ---------------- fused f32 -> bf16 conversion (4 srcs, contiguous dst) ----
struct us4 { unsigned short a, b, c, d; };
__global__ __launch_bounds__(256) void cvt4_f32_bf16(
    const float* __restrict__ s0, const float* __restrict__ s1,
    const float* __restrict__ s2, const float* __restrict__ s3,
    unsigned short* __restrict__ dst, int c0, int c1, int c2, int n4)
{
    int i = blockIdx.x * 256 + threadIdx.x;
    if (i >= n4) return;
    const float* s; int off;
    if (i < c0)      { s = s0; off = i; }
    else if (i < c1) { s = s1; off = i - c0; }
    else if (i < c2) { s = s2; off = i - c1; }
    else             { s = s3; off = i - c2; }
    float4 v = ((const float4*)s)[off];
    us4 o = { f2bf(v.x), f2bf(v.y), f2bf(v.z), f2bf(v.w) };
    ((us4*)dst)[i] = o;
}

// ---------------- 256x256 pipelined GEMM: C = A @ Bt^T (bf16, f32 acc) -----
// 8 waves (2M x 4N), per-wave 128x64 output, BK=64, double-buffered LDS
// tiles (128 KiB) AND double-buffered register fragments (a0/b0, a1/b1).
// 2 phases per K-tile (one k-half each, 32 MFMA): each phase issues the
// NEXT phase's 12 ds_reads, then runs MFMA on the CURRENT set -> the LDS
// drain overlaps the MFMA region (separate pipes). Only 2 barriers/K-tile:
//   lgkmcnt(0)+barrier  before STAGE into a buffer (all reads of it done)
//   vmcnt(8)+barrier    before reading next buffer (counted; 8 loads for
//                       the tile-after remain in flight, never drained)
// LDS layout 256x64, XOR-8 source pre-swizzle (linear LDS dest) ->
// conflict-free ds_read_b128 (verified: SQ_LDS_BANK_CONFLICT = 0).
// EPI 0: col<6144 -> scatter Q/K/V [b][h][t][d]; col>=6144 -> sigmoid -> Gb
// EPI 2: plain f32 -> C
template <int EPI>
__global__ __launch_bounds__(512, 2) void gemm256(
    const unsigned short* __restrict__ A, const unsigned short* __restrict__ Bt,
    void* __restrict__ Cv,
    unsigned short* __restrict__ Qp, unsigned short* __restrict__ Kp,
    unsigned short* __restrict__ Vp, unsigned short* __restrict__ Gb,
    int M, int N, int K)
{
    __shared__ __attribute__((aligned(16))) unsigned short lA[2][16384];
    __shared__ __attribute__((aligned(16))) unsigned short lB[2][16384];

    const int tid  = threadIdx.x;
    const int lane = tid & 63, wave = tid >> 6;
    const int quad = lane >> 4, lr = lane & 15;
    const int wm   = (wave >> 2) * 128;   // 0 / 128
    const int wn   = (wave & 3) * 64;     // 0 / 64 / 128 / 192
    const int lsw  = lr & 7;

    // XCD-aware bijective swizzle, column-major within each XCD chunk
    // (round-2 verified: FETCH_SIZE 562 -> 203 MB). gridDim.y % 8 == 0.
    const int lin = (int)(blockIdx.y * gridDim.x + blockIdx.x);
    const int xcd = lin & 7, j = lin >> 3;
    const int RPC = (int)gridDim.y >> 3;
    const int bm  = xcd * RPC + (j % RPC);
    const int bn  = j / RPC;

    const unsigned short* Ab = A  + (long long)bm * 256 * K;
    const unsigned short* Bb = Bt + (long long)bn * 256 * K;

    // staging: full 256x64 tile = 4 sweeps x (512 thr x 16B) = 4 GLD16/thr.
    // row = w*64 + (tid>>3); group g = tid&7; swizzle key (row&7) is
    // sweep-invariant -> one precomputed offset.
    const int r0 = tid >> 3, g0 = tid & 7;
    const long long gbase = (long long)r0 * K + ((g0 ^ (r0 & 7)) * 8);
    const int lbase = tid * 8;

#define STAGE4(lds, gb, kt)                                                    \
    _Pragma("unroll") for (int w = 0; w < 4; ++w)                              \
        GLD16((lds) + w * 4096 + lbase,                                        \
              (gb) + (long long)w * 64 * K + (kt) + gbase);

    f32x4 acc[8][4] = {};
    bf16x8 a0[8], b0[4], a1[8], b1[4];

#define LDA8(F, buf, s)                                                        \
    _Pragma("unroll") for (int i = 0; i < 8; ++i)                              \
        F[i] = *(const bf16x8*)((buf) + (wm + i * 16 + lr) * 64 +              \
                                ((((s) * 4 + quad) ^ lsw) * 8));
#define LDB4(F, buf, s)                                                        \
    _Pragma("unroll") for (int j2 = 0; j2 < 4; ++j2)                           \
        F[j2] = *(const bf16x8*)((buf) + (wn + j2 * 16 + lr) * 64 +            \
                                 ((((s) * 4 + quad) ^ lsw) * 8));
#define MFMAS(FA, FB)                                                          \
    _Pragma("unroll") for (int i = 0; i < 8; ++i)                              \
    _Pragma("unroll") for (int j2 = 0; j2 < 4; ++j2)                           \
        acc[i][j2] = MFMA16(FA[i], FB[j2], acc[i][j2]);

#define BARR()  asm volatile("s_barrier" ::: "memory")
#define LGKM0() asm volatile("s_waitcnt lgkmcnt(0)" ::: "memory")
#define VM8()   asm volatile("s_waitcnt vmcnt(8)" ::: "memory")
#define SBAR()  __builtin_amdgcn_sched_barrier(0)
#define MCLUST(FA, FB)                                                         \
    do { SBAR(); __builtin_amdgcn_s_setprio(1); MFMAS(FA, FB);                 \
         __builtin_amdgcn_s_setprio(0); SBAR(); } while (0)

    // ---- prologue: stage tiles 0,1; load F0 = s0 of tile 0 ----
    STAGE4(lA[0], Ab, 0);  STAGE4(lB[0], Bb, 0);
    STAGE4(lA[1], Ab, 64); STAGE4(lB[1], Bb, 64);
    VM8();   // tile0's 8 loads landed (own slice); tile1's 8 in flight
    BARR();
    LDA8(a0, lA[0], 0); LDB4(b0, lB[0], 0);

    const int NT = K >> 6;
    for (int it = 0; it < (NT >> 1); ++it) {
        const int knu = (2 * it + 2 < NT) ? (2 * it + 2) * 64 : 0; // clamp tail
        const int knv = (2 * it + 3 < NT) ? (2 * it + 3) * 64 : 0;
        // ==== tile u = 2it (buf0) ====
        // PhA: issue s1 reads; MFMA s0 (drain overlaps)
        LDA8(a1, lA[0], 1); LDB4(b1, lB[0], 1);
        MCLUST(a0, b0);
        LGKM0(); BARR();                 // all reads of buf0 done (all waves)
        // PhB: stage u+2 -> buf0; counted vmcnt -> buf1 ready; issue s0(v);
        //      MFMA s1 (drain + stage ride under it)
        STAGE4(lA[0], Ab, knu); STAGE4(lB[0], Bb, knu);
        VM8(); BARR();                   // tile v landed in buf1 (all waves)
        LDA8(a0, lA[1], 0); LDB4(b0, lB[1], 0);
        MCLUST(a1, b1);
        // ==== tile v = 2it+1 (buf1) ====
        LDA8(a1, lA[1], 1); LDB4(b1, lB[1], 1);
        MCLUST(a0, b0);
        LGKM0(); BARR();                 // all reads of buf1 done
        STAGE4(lA[1], Ab, knv); STAGE4(lB[1], Bb, knv);
        VM8(); BARR();                   // tile u+2 landed in buf0
        LDA8(a0, lA[0], 0); LDB4(b0, lB[0], 0);
        MCLUST(a1, b1);
    }
    asm volatile("s_waitcnt vmcnt(0)" ::: "memory");  // drain before LDS dealloc

    // ---- epilogue ----
#pragma unroll
    for (int i = 0; i < 8; ++i)
#pragma unroll
        for (int j2 = 0; j2 < 4; ++j2)
#pragma unroll
            for (int r = 0; r < 4; ++r) {
                int row = bm * 256 + wm + i * 16 + quad * 4 + r;
                int col = bn * 256 + wn + j2 * 16 + lr;
                float vv = acc[i][j2][r];
                if (EPI == 0) {
                    if (col < 6144) {
                        int tens = col >> 11, h = (col >> 7) & 15, e = col & 127;
                        int b = row >> 12, t = row & 4095;
                        long long dst = (((long long)(b * 16 + h)) * 4096 + t) * 128 + e;
                        unsigned short* P = (tens == 0) ? Qp : ((tens == 1) ? Kp : Vp);
                        P[dst] = f2bf(vv);
                    } else {
                        vv = 1.0f / (1.0f + __expf(-vv));
                        Gb[(long long)row * 2048 + (col - 6144)] = f2bf(vv);
                    }
                } else {
                    ((float*)Cv)[(long long)row * N + col] = vv;
                }
            }
#undef STAGE4
#undef LDA8
#undef LDB4
#undef MFMAS
#undef BARR
#undef LGKM0
#undef VM8
#undef SBAR
#undef MCLUST
}

// ---------------- RMSNorm + RoPE on q,k (in place, [b][h][t][d]) -----------
__global__ __launch_bounds__(256) void norm_rope(
    unsigned short* __restrict__ Qp, unsigned short* __restrict__ Kp,
    const float* __restrict__ qw, const float* __restrict__ kw,
    const int* __restrict__ pos_ids)
{
    const int bid  = blockIdx.x;            // b*16384 + h*1024 + tg
    const int tg   = bid & 1023, h = (bid >> 10) & 15, b = bid >> 14;
    const int wave = threadIdx.x >> 6, lane = threadIdx.x & 63;
    const int t    = tg * 4 + wave;
    const long long rowbase = (((long long)(b * 16 + h)) * 4096 + t) * 128;
    const int pos = pos_ids[b * 4096 + t];
    const int d0  = lane * 2;

    float c0 = 1.f, s0 = 0.f, c1 = 1.f, s1 = 0.f;
    if (lane < 32) {
        float fj0 = (float)(d0 & 31), fj1 = (float)((d0 + 1) & 31);
        float if0 = exp2f(-fj0 * 0.4152410118609203f);  // log2(10000)/32
        float if1 = exp2f(-fj1 * 0.4152410118609203f);
        sincosf((float)pos * if0, &s0, &c0);
        sincosf((float)pos * if1, &s1, &c1);
    }
    const float w0q = qw[d0], w1q = qw[d0 + 1];
    const float w0k = kw[d0], w1k = kw[d0 + 1];

#pragma unroll
    for (int which = 0; which < 2; ++which) {
        unsigned short* P = which ? Kp : Qp;
        float w0 = which ? w0k : w0q, w1 = which ? w1k : w1q;
        unsigned u = *(const unsigned*)(P + rowbase + d0);
        float x0 = bf2f(u & 0xFFFF), x1 = bf2f(u >> 16);
        float ss = x0 * x0 + x1 * x1;
#pragma unroll
        for (int off = 32; off; off >>= 1) ss += __shfl_xor(ss, off);
        float r  = rsqrtf(ss * (1.0f / 128.0f) + 1e-6f);
        float xn0 = x0 * r * w0;
        float xn1 = x1 * r * w1;
        float p0 = __shfl_xor(xn0, 16);
        float p1 = __shfl_xor(xn1, 16);
        float y0, y1;
        if (d0 < 32)      { y0 = xn0 * c0 - p0 * s0; y1 = xn1 * c1 - p1 * s1; }
        else if (d0 < 64) { y0 = xn0 * c0 + p0 * s0; y1 = xn1 * c1 + p1 * s1; }
        else              { y0 = xn0; y1 = xn1; }
        if (which == 0) { y0 *= 0.08838834764831845f; y1 *= 0.08838834764831845f; }
        *(unsigned*)(P + rowbase + d0) =
            (unsigned)f2bf(y0) | ((unsigned)f2bf(y1) << 16);
    }
}

// ---------------- GLA phase A: per-chunk intra + update matrix -------------
__global__ __launch_bounds__(256) void gla_chunk(
    const unsigned short* __restrict__ Qp, const unsigned short* __restrict__ Kp,
    const unsigned short* __restrict__ Vp,
    unsigned short* __restrict__ Oint, unsigned short* __restrict__ Ubuf)
{
    __shared__ __attribute__((aligned(16))) unsigned short sK[64 * 136];
    __shared__ __attribute__((aligned(16))) unsigned short sVT[128 * 72];
    __shared__ __attribute__((aligned(16))) unsigned short sKT[128 * 72];
    __shared__ __attribute__((aligned(16))) unsigned short sAtt[64 * 72];

    const int bid = blockIdx.x;
    const int n = bid & 63, h = (bid >> 6) & 15, b = bid >> 10;
    const int tid = threadIdx.x, wave = tid >> 6, lane = tid & 63;
    const int quad = lane >> 4, lr = lane & 15;
    const float gl2 = -exp2f(-0.5f * (float)(h + 1)) * GSCALE * LOG2E;

    const long long rb = (((long long)(b * 16 + h)) * 4096 + (long long)n * 64) * 128;

    const int cS = wave * 16 + lr;
    const float qsc = exp2f(gl2 * (float)cS);
    bf16x8 qf[4];
#pragma unroll
    for (int ks = 0; ks < 4; ++ks) {
        union { uint4 v; unsigned short s[8]; } in, ou;
        in.v = *(const uint4*)(Qp + rb + cS * 128 + ks * 32 + quad * 8);
#pragma unroll
        for (int j = 0; j < 8; ++j) ou.s[j] = f2bf(bf2f(in.s[j]) * qsc);
        qf[ks] = *(bf16x8*)&ou;
    }
#pragma unroll
    for (int rr = 0; rr < 4; ++rr) {
        int idx = rr * 256 + tid;
        int c = idx >> 4, d8 = (idx & 15) << 3;
        *(uint4*)(sK + c * 136 + d8) = *(const uint4*)(Kp + rb + c * 128 + d8);
    }
#pragma unroll
    for (int rr = 0; rr < 4; ++rr) {
        int idx = rr * 256 + tid;
        int c = idx & 63, g8 = (idx >> 6) << 3;
        union { uint4 v; unsigned short s[8]; } vv, kk;
        vv.v = *(const uint4*)(Vp + rb + c * 128 + g8);
        kk.v = *(const uint4*)(Kp + rb + c * 128 + g8);
        float kdsc = exp2f(gl2 * (float)(64 - c));
#pragma unroll
        for (int j = 0; j < 8; ++j) {
            sVT[(g8 + j) * 72 + c] = vv.s[j];
            sKT[(g8 + j) * 72 + c] = f2bf(bf2f(kk.s[j]) * kdsc);
        }
    }
    __syncthreads();

    f32x4 aacc[4] = {};
#pragma unroll
    for (int nj = 0; nj < 4; ++nj)
#pragma unroll
        for (int ks = 0; ks < 4; ++ks) {
            bf16x8 bf = *(const bf16x8*)(sK + (nj * 16 + lr) * 136 + ks * 32 + quad * 8);
            aacc[nj] = MFMA16(qf[ks], bf, aacc[nj]);
        }
#pragma unroll
    for (int nj = 0; nj < 4; ++nj) {
        int c2 = nj * 16 + lr;
        float colf = exp2f(-gl2 * (float)c2);
#pragma unroll
        for (int r = 0; r < 4; ++r) {
            int c = wave * 16 + quad * 4 + r;
            sAtt[c * 72 + c2] = f2bf((c >= c2) ? aacc[nj][r] * colf : 0.0f);
        }
    }
    f32x4 Sacc[2][8] = {};
#pragma unroll
    for (int me = 0; me < 2; ++me)
#pragma unroll
        for (int ks = 0; ks < 2; ++ks) {
            bf16x8 af = *(const bf16x8*)(sVT + (wave * 32 + me * 16 + lr) * 72 + ks * 32 + quad * 8);
#pragma unroll
            for (int dj = 0; dj < 8; ++dj) {
                bf16x8 bf = *(const bf16x8*)(sKT + (dj * 16 + lr) * 72 + ks * 32 + quad * 8);
                Sacc[me][dj] = MFMA16(af, bf, Sacc[me][dj]);
            }
        }
    const long long ub = ((long long)((b * 16 + h) * 64 + n)) * 16384;
#pragma unroll
    for (int me = 0; me < 2; ++me)
#pragma unroll
        for (int r = 0; r < 4; ++r) {
            int e = wave * 32 + me * 16 + quad * 4 + r;
#pragma unroll
            for (int dj = 0; dj < 8; ++dj)
                Ubuf[ub + e * 128 + dj * 16 + lr] = f2bf(Sacc[me][dj][r]);
        }
    __syncthreads();

    f32x4 oacc[8] = {};
#pragma unroll
    for (int ks = 0; ks < 2; ++ks) {
        bf16x8 af = *(const bf16x8*)(sAtt + cS * 72 + ks * 32 + quad * 8);
#pragma unroll
        for (int ej = 0; ej < 8; ++ej) {
            bf16x8 bf = *(const bf16x8*)(sVT + (ej * 16 + lr) * 72 + ks * 32 + quad * 8);
            oacc[ej] = MFMA16(af, bf, oacc[ej]);
        }
    }
#pragma unroll
    for (int ej = 0; ej < 8; ++ej)
#pragma unroll
        for (int r = 0; r < 4; ++r) {
            int c = wave * 16 + quad * 4 + r;
            long long off = ((long long)(b * 4096 + n * 64 + c)) * 2048 + h * 128 + ej * 16 + lr;
            Oint[off] = f2bf(oacc[ej][r]);
        }
}

// ---------------- GLA phase B: chunk-level prefix scan ---------------------
__global__ __launch_bounds__(256) void gla_scan(
    const unsigned short* __restrict__ Ubuf, unsigned short* __restrict__ STbuf)
{
    const int bid = blockIdx.x;
    const int es = bid & 7, bh = bid >> 3;
    const int h = bh & 15;
    const float gl2 = -exp2f(-0.5f * (float)(h + 1)) * GSCALE * LOG2E;
    const float chd = exp2f(gl2 * 64.0f);
    const int tid = threadIdx.x;
    const long long base = (long long)bh * 64 * 16384 + es * 2048 + tid * 8;
    float st[8] = {};
    for (int n = 0; n < 64; ++n) {
        long long a = base + (long long)n * 16384;
        union { uint4 v; unsigned short s[8]; } u, o;
        u.v = *(const uint4*)(Ubuf + a);
#pragma unroll
        for (int j = 0; j < 8; ++j) o.s[j] = f2bf(st[j]);
        *(uint4*)(STbuf + a) = o.v;
#pragma unroll
        for (int j = 0; j < 8; ++j) st[j] = st[j] * chd + bf2f(u.s[j]);
    }
}

// ---------------- GLA phase C: inter + group-RMSNorm * gate ----------------
__global__ __launch_bounds__(256) void gla_inter(
    const unsigned short* __restrict__ Qp, const unsigned short* __restrict__ STbuf,
    unsigned short* __restrict__ Ob, const unsigned short* __restrict__ Gb,
    const float* __restrict__ W)
{
    __shared__ __attribute__((aligned(16))) unsigned short sST[128 * 136];
    const int bid = blockIdx.x;
    const int n = bid & 63, h = (bid >> 6) & 15, b = bid >> 10;
    const int tid = threadIdx.x, wave = tid >> 6, lane = tid & 63;
    const int quad = lane >> 4, lr = lane & 15;
    const float gl2 = -exp2f(-0.5f * (float)(h + 1)) * GSCALE * LOG2E;
    const long long rb = (((long long)(b * 16 + h)) * 4096 + (long long)n * 64) * 128;
    const long long stb = ((long long)((b * 16 + h) * 64 + n)) * 16384;

#pragma unroll
    for (int rr = 0; rr < 8; ++rr) {
        int idx = rr * 256 + tid;
        int row = idx >> 4, d8 = (idx & 15) << 3;
        *(uint4*)(sST + row * 136 + d8) = *(const uint4*)(STbuf + stb + row * 128 + d8);
    }
    const int cS = wave * 16 + lr;
    const float qsc = exp2f(gl2 * (float)cS);
    bf16x8 qf[4];
#pragma unroll
    for (int ks = 0; ks < 4; ++ks) {
        union { uint4 v; unsigned short s[8]; } in, ou;
        in.v = *(const uint4*)(Qp + rb + cS * 128 + ks * 32 + quad * 8);
#pragma unroll
        for (int j = 0; j < 8; ++j) ou.s[j] = f2bf(bf2f(in.s[j]) * qsc);
        qf[ks] = *(bf16x8*)&ou;
    }
    __syncthreads();

    f32x4 oacc[8] = {};
#pragma unroll
    for (int ks = 0; ks < 4; ++ks)
#pragma unroll
        for (int ej = 0; ej < 8; ++ej) {
            bf16x8 bf = *(const bf16x8*)(sST + (ej * 16 + lr) * 136 + ks * 32 + quad * 8);
            oacc[ej] = MFMA16(qf[ks], bf, oacc[ej]);
        }

    float w[8];
#pragma unroll
    for (int ej = 0; ej < 8; ++ej) w[ej] = W[h * 128 + ej * 16 + lr];

    float ss[4] = {};
#pragma unroll
    for (int r = 0; r < 4; ++r) {
        int c = wave * 16 + quad * 4 + r;
        long long off = ((long long)(b * 4096 + n * 64 + c)) * 2048 + h * 128;
#pragma unroll
        for (int ej = 0; ej < 8; ++ej) {
            float v = oacc[ej][r] + bf2f(Ob[off + ej * 16 + lr]);
            oacc[ej][r] = v;
            ss[r] += v * v;
        }
    }
#pragma unroll
    for (int r = 0; r < 4; ++r) {
#pragma unroll
        for (int o2 = 1; o2 < 16; o2 <<= 1) ss[r] += __shfl_xor(ss[r], o2);
        float rn = rsqrtf(ss[r] * (1.0f / 128.0f) + 1e-6f);
        int c = wave * 16 + quad * 4 + r;
        long long off = ((long long)(b * 4096 + n * 64 + c)) * 2048 + h * 128;
#pragma unroll
        for (int ej = 0; ej < 8; ++ej) {
            float g = bf2f(Gb[off + ej * 16 + lr]);
            Ob[off + ej * 16 + lr] = f2bf(oacc[ej][r] * rn * w[ej] * g);
        }
    }
}

// ---------------- launcher ----------------
extern "C" void kernel_launch(void* const* d_in, const int* in_sizes, int n_in,
                              void* d_out, int out_size, void* d_ws, size_t ws_size,
                              hipStream_t stream)
{
    const float* hid   = (const float*)d_in[0];
    const float* w_qkv = (const float*)d_in[1];
    const float* q_ln  = (const float*)d_in[2];
    const float* k_ln  = (const float*)d_in[3];
    const float* g_nw  = (const float*)d_in[4];
    const float* w_g   = (const float*)d_in[5];
    const float* w_d   = (const float*)d_in[6];
    const int*   pos   = (const int*)d_in[7];

    const size_t PLANE = (size_t)2 * 16 * 4096 * 128;  // 16.78M elems
    unsigned short* Qp    = (unsigned short*)d_ws;
    unsigned short* Kp    = Qp + PLANE;
    unsigned short* Vp    = Kp + PLANE;
    unsigned short* Ob    = Vp + PLANE;
    unsigned short* Gb    = Ob + PLANE;
    unsigned short* hidb  = Gb + PLANE;                  // 8192*2048
    unsigned short* wqkvb = hidb + (size_t)8192 * 2048;  // 6144*2048  (qkv ‖ gate)
    unsigned short* wgb   = wqkvb + (size_t)6144 * 2048; // 2048*2048  (contiguous!)
    unsigned short* wdb   = wgb + (size_t)2048 * 2048;   // 2048*2048
    // aliases (lifetimes disjoint by stream order):
    unsigned short* Ubuf  = hidb;  // 33.55M elems == hidb+wqkvb+wgb exactly
    unsigned short* STbuf = Kp;    // 33.55M elems == Kp+Vp

    dim3 blk(256);
    const int c0 = 8192 * 2048 / 4;                 // hid
    const int c1 = c0 + 6144 * 2048 / 4;            // w_qkv
    const int c2 = c1 + 2048 * 2048 / 4;            // w_g
    const int n4 = c2 + 2048 * 2048 / 4;            // w_d
    cvt4_f32_bf16<<<(n4 + 255) / 256, blk, 0, stream>>>(
        hid, w_qkv, w_g, w_d, hidb, c0, c1, c2, n4);

    // merged QKV+gate projection: B = [w_qkv ; w_g], N=8192 (256² pipelined)
    gemm256<0><<<dim3(32, 32), dim3(512), 0, stream>>>(
        hidb, wqkvb, nullptr, Qp, Kp, Vp, Gb, 8192, 8192, 2048);
    // q/k rmsnorm + rope (+ q * D^-0.5), in place
    norm_rope<<<32768, blk, 0, stream>>>(Qp, Kp, q_ln, k_ln, pos);
    // GLA: per-chunk work (parallel) -> scan (cheap) -> inter + norm*gate
    gla_chunk<<<2048, blk, 0, stream>>>(Qp, Kp, Vp, Ob, Ubuf);
    gla_scan<<<256, blk, 0, stream>>>(Ubuf, STbuf);
    gla_inter<<<2048, blk, 0, stream>>>(Qp, STbuf, Ob, Gb, g_nw);
    // output projection -> f32 d_out (256² pipelined)
    gemm256<2><<<dim3(8, 32), dim3(512), 0, stream>>>(
        Ob, wdb, d_out, nullptr, nullptr, nullptr, nullptr, 8192, 2048, 2048);
}

// Round 5
// 610.721 us; speedup vs baseline: 1.1488x; 1.0252x over previous
//
#include <hip/hip_runtime.h>
#include <math.h>

// ---------------- common helpers ----------------
typedef short bf16x8 __attribute__((ext_vector_type(8)));
typedef float f32x4 __attribute__((ext_vector_type(4)));

#define LOG2E 1.4426950408889634f
#define GSCALE 0.6451712903225806f   /* 1 - 11/31 + 1e-5 */

__device__ __forceinline__ float bf2f(unsigned short h) {
    union { unsigned u; float f; } v; v.u = ((unsigned)h) << 16; return v.f;
}
__device__ __forceinline__ unsigned short f2bf(float f) {
    union { float f; unsigned u; } v; v.f = f;
    unsigned r = v.u + 0x7FFFu + ((v.u >> 16) & 1u);
    return (unsigned short)(r >> 16);
}

#define GLD16(lds, g)                                                          \
    __builtin_amdgcn_global_load_lds(                                          \
        (const __attribute__((address_space(1))) void*)(g),                    \
        (__attribute__((address_space(3))) void*)(lds), 16, 0, 0)

#define MFMA16(a, b, c) __builtin_amdgcn_mfma_f32_16x16x32_bf16(a, b, c, 0, 0, 0)

// raw ds_read_b128: invisible to the compiler's waitcnt pass (we hand-count)
__device__ __forceinline__ void dsr128(bf16x8& d, const unsigned short* p) {
    unsigned off = (unsigned)(unsigned long long)
        (const __attribute__((address_space(3))) unsigned short*)p;
    asm volatile("ds_read_b128 %0, %1" : "=v"(d) : "v"(off));
}

// ---------------- fused f32 -> bf16 conversion (4 srcs, contiguous dst) ----
struct us4 { unsigned short a, b, c, d; };
__global__ __launch_bounds__(256) void cvt4_f32_bf16(
    const float* __restrict__ s0, const float* __restrict__ s1,
    const float* __restrict__ s2, const float* __restrict__ s3,
    unsigned short* __restrict__ dst, int c0, int c1, int c2, int n4)
{
    int i = blockIdx.x * 256 + threadIdx.x;
    if (i >= n4) return;
    const float* s; int off;
    if (i < c0)      { s = s0; off = i; }
    else if (i < c1) { s = s1; off = i - c0; }
    else if (i < c2) { s = s2; off = i - c1; }
    else             { s = s3; off = i - c2; }
    float4 v = ((const float4*)s)[off];
    us4 o = { f2bf(v.x), f2bf(v.y), f2bf(v.z), f2bf(v.w) };
    ((us4*)dst)[i] = o;
}

// ---------------- 256x256 pipelined GEMM: C = A @ Bt^T (bf16, f32 acc) -----
// 8 waves (2M x 4N), per-wave 128x64 output, BK=64, double-buffered LDS
// (128 KiB) + double-buffered register fragments F0/F1. ALL fragment LDS
// reads are raw inline-asm ds_read_b128 with HAND-COUNTED waits, so the
// compiler's (conservative) waitcnt pass cannot inject lgkmcnt(0) in front
// of the MFMA clusters (the round-1..3 serializer). Per K-tile:
//   PhA: 12 asm reads (slice1) ; lgkmcnt(12) -> slice0 ready (FIFO) ;
//        32 MFMA(F0) overlap the drain ; lgkmcnt(0)+barrier (overwrite ok)
//   PhB: stage next+1 tile (8 GLD) ; vmcnt(8)+barrier (next tile landed) ;
//        12 asm reads (next slice0) ; lgkmcnt(12) ; 32 MFMA(F1)
// XOR-8 source pre-swizzle, conflict-free (SQ_LDS_BANK_CONFLICT = 0).
// EPI 0: col<6144 -> scatter Q/K/V [b][h][t][d]; col>=6144 -> sigmoid -> Gb
// EPI 2: plain f32 -> C
template <int EPI>
__global__ __launch_bounds__(512, 2) void gemm256(
    const unsigned short* __restrict__ A, const unsigned short* __restrict__ Bt,
    void* __restrict__ Cv,
    unsigned short* __restrict__ Qp, unsigned short* __restrict__ Kp,
    unsigned short* __restrict__ Vp, unsigned short* __restrict__ Gb,
    int M, int N, int K)
{
    __shared__ __attribute__((aligned(16))) unsigned short lA[2][16384];
    __shared__ __attribute__((aligned(16))) unsigned short lB[2][16384];

    const int tid  = threadIdx.x;
    const int lane = tid & 63, wave = tid >> 6;
    const int quad = lane >> 4, lr = lane & 15;
    const int wm   = (wave >> 2) * 128;   // 0 / 128
    const int wn   = (wave & 3) * 64;     // 0 / 64 / 128 / 192
    const int lsw  = lr & 7;

    // XCD-aware bijective swizzle, column-major within each XCD chunk
    // (verified: FETCH_SIZE 562 -> 203 MB). gridDim.y % 8 == 0.
    const int lin = (int)(blockIdx.y * gridDim.x + blockIdx.x);
    const int xcd = lin & 7, j = lin >> 3;
    const int RPC = (int)gridDim.y >> 3;
    const int bm  = xcd * RPC + (j % RPC);
    const int bn  = j / RPC;

    const unsigned short* Ab = A  + (long long)bm * 256 * K;
    const unsigned short* Bb = Bt + (long long)bn * 256 * K;

    // staging: full 256x64 tile = 4 sweeps x (512 thr x 16B). LDS dest
    // linear; global src pre-swizzled: LDS slot g of row r <- group g^(r&7).
    const int r0 = tid >> 3, g0 = tid & 7;
    const long long gbase = (long long)r0 * K + ((g0 ^ (r0 & 7)) * 8);
    const int lbase = tid * 8;

#define STAGE4(lds, gb, kt)                                                    \
    _Pragma("unroll") for (int w = 0; w < 4; ++w)                              \
        GLD16((lds) + w * 4096 + lbase,                                        \
              (gb) + (long long)w * 64 * K + (kt) + gbase);

    f32x4 acc[8][4] = {};
    bf16x8 a0[8], b0[4], a1[8], b1[4];

#define LDA8A(F, buf, s)                                                       \
    _Pragma("unroll") for (int i = 0; i < 8; ++i)                              \
        dsr128(F[i], (buf) + (wm + i * 16 + lr) * 64 +                         \
                     ((((s) * 4 + quad) ^ lsw) * 8));
#define LDB4A(F, buf, s)                                                       \
    _Pragma("unroll") for (int j2 = 0; j2 < 4; ++j2)                           \
        dsr128(F[j2], (buf) + (wn + j2 * 16 + lr) * 64 +                       \
                      ((((s) * 4 + quad) ^ lsw) * 8));
#define MFMAS(FA, FB)                                                          \
    _Pragma("unroll") for (int i = 0; i < 8; ++i)                              \
    _Pragma("unroll") for (int j2 = 0; j2 < 4; ++j2)                           \
        acc[i][j2] = MFMA16(FA[i], FB[j2], acc[i][j2]);

#define BARR()   asm volatile("s_barrier" ::: "memory")
#define LGKM0()  asm volatile("s_waitcnt lgkmcnt(0)" ::: "memory")
#define LGKM12() asm volatile("s_waitcnt lgkmcnt(12)" ::: "memory")
#define VM8()    asm volatile("s_waitcnt vmcnt(8)" ::: "memory")
#define SBAR()   __builtin_amdgcn_sched_barrier(0)
#define MCLUST(FA, FB)                                                         \
    do { SBAR(); __builtin_amdgcn_s_setprio(1); MFMAS(FA, FB);                 \
         __builtin_amdgcn_s_setprio(0); SBAR(); } while (0)

    // ---- prologue: stage tiles 0,1; asm-read F0 = slice0 of tile 0 ----
    STAGE4(lA[0], Ab, 0);  STAGE4(lB[0], Bb, 0);
    STAGE4(lA[1], Ab, 64); STAGE4(lB[1], Bb, 64);
    VM8();   // tile0's 8 loads landed (FIFO); tile1's 8 in flight
    BARR();
    LDA8A(a0, lA[0], 0); LDB4A(b0, lB[0], 0);   // 12 outstanding lgkm

    const int NT = K >> 6;
    for (int it = 0; it < (NT >> 1); ++it) {
        const int knu = (2 * it + 2 < NT) ? (2 * it + 2) * 64 : 0; // clamp tail
        const int knv = (2 * it + 3 < NT) ? (2 * it + 3) * 64 : 0;
        // ==== tile u = 2it (buf0) ====
        LDA8A(a1, lA[0], 1); LDB4A(b1, lB[0], 1);   // F1 <- buf0.s1
        LGKM12();                                    // F0 ready (oldest 12)
        MCLUST(a0, b0);                              // F1 drain rides under
        LGKM0(); BARR();                             // all buf0 reads done
        STAGE4(lA[0], Ab, knu); STAGE4(lB[0], Bb, knu);  // tile u+2 -> buf0
        VM8(); BARR();                               // tile v landed (buf1)
        LDA8A(a0, lA[1], 0); LDB4A(b0, lB[1], 0);   // F0 <- buf1.s0
        LGKM12();                                    // F1 ready
        MCLUST(a1, b1);                              // F0 drain + stage ride
        // ==== tile v = 2it+1 (buf1) ====
        LDA8A(a1, lA[1], 1); LDB4A(b1, lB[1], 1);   // F1 <- buf1.s1
        LGKM12();                                    // F0 ready
        MCLUST(a0, b0);
        LGKM0(); BARR();                             // all buf1 reads done
        STAGE4(lA[1], Ab, knv); STAGE4(lB[1], Bb, knv);  // tile v+2 -> buf1
        VM8(); BARR();                               // tile u+2 landed (buf0)
        LDA8A(a0, lA[0], 0); LDB4A(b0, lB[0], 0);   // F0 <- buf0.s0
        LGKM12();                                    // F1 ready
        MCLUST(a1, b1);
    }
    asm volatile("s_waitcnt vmcnt(0) lgkmcnt(0)" ::: "memory");  // full drain

    // ---- epilogue ----
#pragma unroll
    for (int i = 0; i < 8; ++i)
#pragma unroll
        for (int j2 = 0; j2 < 4; ++j2)
#pragma unroll
            for (int r = 0; r < 4; ++r) {
                int row = bm * 256 + wm + i * 16 + quad * 4 + r;
                int col = bn * 256 + wn + j2 * 16 + lr;
                float vv = acc[i][j2][r];
                if (EPI == 0) {
                    if (col < 6144) {
                        int tens = col >> 11, h = (col >> 7) & 15, e = col & 127;
                        int b = row >> 12, t = row & 4095;
                        long long dst = (((long long)(b * 16 + h)) * 4096 + t) * 128 + e;
                        unsigned short* P = (tens == 0) ? Qp : ((tens == 1) ? Kp : Vp);
                        P[dst] = f2bf(vv);
                    } else {
                        vv = 1.0f / (1.0f + __expf(-vv));
                        Gb[(long long)row * 2048 + (col - 6144)] = f2bf(vv);
                    }
                } else {
                    ((float*)Cv)[(long long)row * N + col] = vv;
                }
            }
#undef STAGE4
#undef LDA8A
#undef LDB4A
#undef MFMAS
#undef BARR
#undef LGKM0
#undef LGKM12
#undef VM8
#undef SBAR
#undef MCLUST
}

// ---------------- RMSNorm + RoPE on q,k (in place, [b][h][t][d]) -----------
__global__ __launch_bounds__(256) void norm_rope(
    unsigned short* __restrict__ Qp, unsigned short* __restrict__ Kp,
    const float* __restrict__ qw, const float* __restrict__ kw,
    const int* __restrict__ pos_ids)
{
    const int bid  = blockIdx.x;            // b*16384 + h*1024 + tg
    const int tg   = bid & 1023, h = (bid >> 10) & 15, b = bid >> 14;
    const int wave = threadIdx.x >> 6, lane = threadIdx.x & 63;
    const int t    = tg * 4 + wave;
    const long long rowbase = (((long long)(b * 16 + h)) * 4096 + t) * 128;
    const int pos = pos_ids[b * 4096 + t];
    const int d0  = lane * 2;

    float c0 = 1.f, s0 = 0.f, c1 = 1.f, s1 = 0.f;
    if (lane < 32) {
        float fj0 = (float)(d0 & 31), fj1 = (float)((d0 + 1) & 31);
        float if0 = exp2f(-fj0 * 0.4152410118609203f);  // log2(10000)/32
        float if1 = exp2f(-fj1 * 0.4152410118609203f);
        sincosf((float)pos * if0, &s0, &c0);
        sincosf((float)pos * if1, &s1, &c1);
    }
    const float w0q = qw[d0], w1q = qw[d0 + 1];
    const float w0k = kw[d0], w1k = kw[d0 + 1];

#pragma unroll
    for (int which = 0; which < 2; ++which) {
        unsigned short* P = which ? Kp : Qp;
        float w0 = which ? w0k : w0q, w1 = which ? w1k : w1q;
        unsigned u = *(const unsigned*)(P + rowbase + d0);
        float x0 = bf2f(u & 0xFFFF), x1 = bf2f(u >> 16);
        float ss = x0 * x0 + x1 * x1;
#pragma unroll
        for (int off = 32; off; off >>= 1) ss += __shfl_xor(ss, off);
        float r  = rsqrtf(ss * (1.0f / 128.0f) + 1e-6f);
        float xn0 = x0 * r * w0;
        float xn1 = x1 * r * w1;
        float p0 = __shfl_xor(xn0, 16);
        float p1 = __shfl_xor(xn1, 16);
        float y0, y1;
        if (d0 < 32)      { y0 = xn0 * c0 - p0 * s0; y1 = xn1 * c1 - p1 * s1; }
        else if (d0 < 64) { y0 = xn0 * c0 + p0 * s0; y1 = xn1 * c1 + p1 * s1; }
        else              { y0 = xn0; y1 = xn1; }
        if (which == 0) { y0 *= 0.08838834764831845f; y1 *= 0.08838834764831845f; }
        *(unsigned*)(P + rowbase + d0) =
            (unsigned)f2bf(y0) | ((unsigned)f2bf(y1) << 16);
    }
}

// ---------------- GLA phase A: per-chunk intra + update matrix -------------
__global__ __launch_bounds__(256) void gla_chunk(
    const unsigned short* __restrict__ Qp, const unsigned short* __restrict__ Kp,
    const unsigned short* __restrict__ Vp,
    unsigned short* __restrict__ Oint, unsigned short* __restrict__ Ubuf)
{
    __shared__ __attribute__((aligned(16))) unsigned short sK[64 * 136];
    __shared__ __attribute__((aligned(16))) unsigned short sVT[128 * 72];
    __shared__ __attribute__((aligned(16))) unsigned short sKT[128 * 72];
    __shared__ __attribute__((aligned(16))) unsigned short sAtt[64 * 72];

    const int bid = blockIdx.x;
    const int n = bid & 63, h = (bid >> 6) & 15, b = bid >> 10;
    const int tid = threadIdx.x, wave = tid >> 6, lane = tid & 63;
    const int quad = lane >> 4, lr = lane & 15;
    const float gl2 = -exp2f(-0.5f * (float)(h + 1)) * GSCALE * LOG2E;

    const long long rb = (((long long)(b * 16 + h)) * 4096 + (long long)n * 64) * 128;

    const int cS = wave * 16 + lr;
    const float qsc = exp2f(gl2 * (float)cS);
    bf16x8 qf[4];
#pragma unroll
    for (int ks = 0; ks < 4; ++ks) {
        union { uint4 v; unsigned short s[8]; } in, ou;
        in.v = *(const uint4*)(Qp + rb + cS * 128 + ks * 32 + quad * 8);
#pragma unroll
        for (int j = 0; j < 8; ++j) ou.s[j] = f2bf(bf2f(in.s[j]) * qsc);
        qf[ks] = *(bf16x8*)&ou;
    }
#pragma unroll
    for (int rr = 0; rr < 4; ++rr) {
        int idx = rr * 256 + tid;
        int c = idx >> 4, d8 = (idx & 15) << 3;
        *(uint4*)(sK + c * 136 + d8) = *(const uint4*)(Kp + rb + c * 128 + d8);
    }
#pragma unroll
    for (int rr = 0; rr < 4; ++rr) {
        int idx = rr * 256 + tid;
        int c = idx & 63, g8 = (idx >> 6) << 3;
        union { uint4 v; unsigned short s[8]; } vv, kk;
        vv.v = *(const uint4*)(Vp + rb + c * 128 + g8);
        kk.v = *(const uint4*)(Kp + rb + c * 128 + g8);
        float kdsc = exp2f(gl2 * (float)(64 - c));
#pragma unroll
        for (int j = 0; j < 8; ++j) {
            sVT[(g8 + j) * 72 + c] = vv.s[j];
            sKT[(g8 + j) * 72 + c] = f2bf(bf2f(kk.s[j]) * kdsc);
        }
    }
    __syncthreads();

    f32x4 aacc[4] = {};
#pragma unroll
    for (int nj = 0; nj < 4; ++nj)
#pragma unroll
        for (int ks = 0; ks < 4; ++ks) {
            bf16x8 bf = *(const bf16x8*)(sK + (nj * 16 + lr) * 136 + ks * 32 + quad * 8);
            aacc[nj] = MFMA16(qf[ks], bf, aacc[nj]);
        }
#pragma unroll
    for (int nj = 0; nj < 4; ++nj) {
        int c2 = nj * 16 + lr;
        float colf = exp2f(-gl2 * (float)c2);
#pragma unroll
        for (int r = 0; r < 4; ++r) {
            int c = wave * 16 + quad * 4 + r;
            sAtt[c * 72 + c2] = f2bf((c >= c2) ? aacc[nj][r] * colf : 0.0f);
        }
    }
    f32x4 Sacc[2][8] = {};
#pragma unroll
    for (int me = 0; me < 2; ++me)
#pragma unroll
        for (int ks = 0; ks < 2; ++ks) {
            bf16x8 af = *(const bf16x8*)(sVT + (wave * 32 + me * 16 + lr) * 72 + ks * 32 + quad * 8);
#pragma unroll
            for (int dj = 0; dj < 8; ++dj) {
                bf16x8 bf = *(const bf16x8*)(sKT + (dj * 16 + lr) * 72 + ks * 32 + quad * 8);
                Sacc[me][dj] = MFMA16(af, bf, Sacc[me][dj]);
            }
        }
    const long long ub = ((long long)((b * 16 + h) * 64 + n)) * 16384;
#pragma unroll
    for (int me = 0; me < 2; ++me)
#pragma unroll
        for (int r = 0; r < 4; ++r) {
            int e = wave * 32 + me * 16 + quad * 4 + r;
#pragma unroll
            for (int dj = 0; dj < 8; ++dj)
                Ubuf[ub + e * 128 + dj * 16 + lr] = f2bf(Sacc[me][dj][r]);
        }
    __syncthreads();

    f32x4 oacc[8] = {};
#pragma unroll
    for (int ks = 0; ks < 2; ++ks) {
        bf16x8 af = *(const bf16x8*)(sAtt + cS * 72 + ks * 32 + quad * 8);
#pragma unroll
        for (int ej = 0; ej < 8; ++ej) {
            bf16x8 bf = *(const bf16x8*)(sVT + (ej * 16 + lr) * 72 + ks * 32 + quad * 8);
            oacc[ej] = MFMA16(af, bf, oacc[ej]);
        }
    }
#pragma unroll
    for (int ej = 0; ej < 8; ++ej)
#pragma unroll
        for (int r = 0; r < 4; ++r) {
            int c = wave * 16 + quad * 4 + r;
            long long off = ((long long)(b * 4096 + n * 64 + c)) * 2048 + h * 128 + ej * 16 + lr;
            Oint[off] = f2bf(oacc[ej][r]);
        }
}

// ---------------- GLA phase B: chunk-level prefix scan ---------------------
__global__ __launch_bounds__(256) void gla_scan(
    const unsigned short* __restrict__ Ubuf, unsigned short* __restrict__ STbuf)
{
    const int bid = blockIdx.x;
    const int es = bid & 7, bh = bid >> 3;
    const int h = bh & 15;
    const float gl2 = -exp2f(-0.5f * (float)(h + 1)) * GSCALE * LOG2E;
    const float chd = exp2f(gl2 * 64.0f);
    const int tid = threadIdx.x;
    const long long base = (long long)bh * 64 * 16384 + es * 2048 + tid * 8;
    float st[8] = {};
    for (int n = 0; n < 64; ++n) {
        long long a = base + (long long)n * 16384;
        union { uint4 v; unsigned short s[8]; } u, o;
        u.v = *(const uint4*)(Ubuf + a);
#pragma unroll
        for (int j = 0; j < 8; ++j) o.s[j] = f2bf(st[j]);
        *(uint4*)(STbuf + a) = o.v;
#pragma unroll
        for (int j = 0; j < 8; ++j) st[j] = st[j] * chd + bf2f(u.s[j]);
    }
}

// ---------------- GLA phase C: inter + group-RMSNorm * gate ----------------
__global__ __launch_bounds__(256) void gla_inter(
    const unsigned short* __restrict__ Qp, const unsigned short* __restrict__ STbuf,
    unsigned short* __restrict__ Ob, const unsigned short* __restrict__ Gb,
    const float* __restrict__ W)
{
    __shared__ __attribute__((aligned(16))) unsigned short sST[128 * 136];
    const int bid = blockIdx.x;
    const int n = bid & 63, h = (bid >> 6) & 15, b = bid >> 10;
    const int tid = threadIdx.x, wave = tid >> 6, lane = tid & 63;
    const int quad = lane >> 4, lr = lane & 15;
    const float gl2 = -exp2f(-0.5f * (float)(h + 1)) * GSCALE * LOG2E;
    const long long rb = (((long long)(b * 16 + h)) * 4096 + (long long)n * 64) * 128;
    const long long stb = ((long long)((b * 16 + h) * 64 + n)) * 16384;

#pragma unroll
    for (int rr = 0; rr < 8; ++rr) {
        int idx = rr * 256 + tid;
        int row = idx >> 4, d8 = (idx & 15) << 3;
        *(uint4*)(sST + row * 136 + d8) = *(const uint4*)(STbuf + stb + row * 128 + d8);
    }
    const int cS = wave * 16 + lr;
    const float qsc = exp2f(gl2 * (float)cS);
    bf16x8 qf[4];
#pragma unroll
    for (int ks = 0; ks < 4; ++ks) {
        union { uint4 v; unsigned short s[8]; } in, ou;
        in.v = *(const uint4*)(Qp + rb + cS * 128 + ks * 32 + quad * 8);
#pragma unroll
        for (int j = 0; j < 8; ++j) ou.s[j] = f2bf(bf2f(in.s[j]) * qsc);
        qf[ks] = *(bf16x8*)&ou;
    }
    __syncthreads();

    f32x4 oacc[8] = {};
#pragma unroll
    for (int ks = 0; ks < 4; ++ks)
#pragma unroll
        for (int ej = 0; ej < 8; ++ej) {
            bf16x8 bf = *(const bf16x8*)(sST + (ej * 16 + lr) * 136 + ks * 32 + quad * 8);
            oacc[ej] = MFMA16(qf[ks], bf, oacc[ej]);
        }

    float w[8];
#pragma unroll
    for (int ej = 0; ej < 8; ++ej) w[ej] = W[h * 128 + ej * 16 + lr];

    float ss[4] = {};
#pragma unroll
    for (int r = 0; r < 4; ++r) {
        int c = wave * 16 + quad * 4 + r;
        long long off = ((long long)(b * 4096 + n * 64 + c)) * 2048 + h * 128;
#pragma unroll
        for (int ej = 0; ej < 8; ++ej) {
            float v = oacc[ej][r] + bf2f(Ob[off + ej * 16 + lr]);
            oacc[ej][r] = v;
            ss[r] += v * v;
        }
    }
#pragma unroll
    for (int r = 0; r < 4; ++r) {
#pragma unroll
        for (int o2 = 1; o2 < 16; o2 <<= 1) ss[r] += __shfl_xor(ss[r], o2);
        float rn = rsqrtf(ss[r] * (1.0f / 128.0f) + 1e-6f);
        int c = wave * 16 + quad * 4 + r;
        long long off = ((long long)(b * 4096 + n * 64 + c)) * 2048 + h * 128;
#pragma unroll
        for (int ej = 0; ej < 8; ++ej) {
            float g = bf2f(Gb[off + ej * 16 + lr]);
            Ob[off + ej * 16 + lr] = f2bf(oacc[ej][r] * rn * w[ej] * g);
        }
    }
}

// ---------------- launcher ----------------
extern "C" void kernel_launch(void* const* d_in, const int* in_sizes, int n_in,
                              void* d_out, int out_size, void* d_ws, size_t ws_size,
                              hipStream_t stream)
{
    const float* hid   = (const float*)d_in[0];
    const float* w_qkv = (const float*)d_in[1];
    const float* q_ln  = (const float*)d_in[2];
    const float* k_ln  = (const float*)d_in[3];
    const float* g_nw  = (const float*)d_in[4];
    const float* w_g   = (const float*)d_in[5];
    const float* w_d   = (const float*)d_in[6];
    const int*   pos   = (const int*)d_in[7];

    const size_t PLANE = (size_t)2 * 16 * 4096 * 128;  // 16.78M elems
    unsigned short* Qp    = (unsigned short*)d_ws;
    unsigned short* Kp    = Qp + PLANE;
    unsigned short* Vp    = Kp + PLANE;
    unsigned short* Ob    = Vp + PLANE;
    unsigned short* Gb    = Ob + PLANE;
    unsigned short* hidb  = Gb + PLANE;                  // 8192*2048
    unsigned short* wqkvb = hidb + (size_t)8192 * 2048;  // 6144*2048  (qkv ‖ gate)
    unsigned short* wgb   = wqkvb + (size_t)6144 * 2048; // 2048*2048  (contiguous!)
    unsigned short* wdb   = wgb + (size_t)2048 * 2048;   // 2048*2048
    // aliases (lifetimes disjoint by stream order):
    unsigned short* Ubuf  = hidb;  // 33.55M elems == hidb+wqkvb+wgb exactly
    unsigned short* STbuf = Kp;    // 33.55M elems == Kp+Vp

    dim3 blk(256);
    const int c0 = 8192 * 2048 / 4;                 // hid
    const int c1 = c0 + 6144 * 2048 / 4;            // w_qkv
    const int c2 = c1 + 2048 * 2048 / 4;            // w_g
    const int n4 = c2 + 2048 * 2048 / 4;            // w_d
    cvt4_f32_bf16<<<(n4 + 255) / 256, blk, 0, stream>>>(
        hid, w_qkv, w_g, w_d, hidb, c0, c1, c2, n4);

    // merged QKV+gate projection: B = [w_qkv ; w_g], N=8192 (256² pipelined)
    gemm256<0><<<dim3(32, 32), dim3(512), 0, stream>>>(
        hidb, wqkvb, nullptr, Qp, Kp, Vp, Gb, 8192, 8192, 2048);
    // q/k rmsnorm + rope (+ q * D^-0.5), in place
    norm_rope<<<32768, blk, 0, stream>>>(Qp, Kp, q_ln, k_ln, pos);
    // GLA: per-chunk work (parallel) -> scan (cheap) -> inter + norm*gate
    gla_chunk<<<2048, blk, 0, stream>>>(Qp, Kp, Vp, Ob, Ubuf);
    gla_scan<<<256, blk, 0, stream>>>(Ubuf, STbuf);
    gla_inter<<<2048, blk, 0, stream>>>(Qp, STbuf, Ob, Gb, g_nw);
    // output projection -> f32 d_out (256² pipelined)
    gemm256<2><<<dim3(8, 32), dim3(512), 0, stream>>>(
        Ob, wdb, d_out, nullptr, nullptr, nullptr, nullptr, 8192, 2048, 2048);
}